// Round 3
// baseline (5133.860 us; speedup 1.0000x reference)
//
#include <hip/hip_runtime.h>

#define HD 128

// 4 rows x 8 cols outer-product FMA on fp32 accumulators.
__device__ __forceinline__ void fma_4x8(float (&acc)[4][8], float4 a, float4 b0, float4 b1) {
  float av[4] = {a.x, a.y, a.z, a.w};
  float bv[8] = {b0.x, b0.y, b0.z, b0.w, b1.x, b1.y, b1.z, b1.w};
#pragma unroll
  for (int i = 0; i < 4; ++i)
#pragma unroll
    for (int j = 0; j < 8; ++j)
      acc[i][j] += av[i] * bv[j];
}

// ---------------- small helper kernels ----------------

__global__ void k_deg(const int* __restrict__ col, float* __restrict__ deg, int E) {
  int e = blockIdx.x * 256 + threadIdx.x;
  if (e < E) atomicAdd(&deg[col[e]], 1.0f);
}

__global__ void k_rdeg(float* __restrict__ deg, int n) {
  int i = blockIdx.x * 256 + threadIdx.x;
  if (i < n) deg[i] = 1.0f / fmaxf(deg[i], 1.0f);
}

__global__ void k_gcnt(const int* __restrict__ batch, float* __restrict__ gcnt, int n) {
  int i = blockIdx.x * 256 + threadIdx.x;
  if (i < n) atomicAdd(&gcnt[batch[i]], 1.0f);
}

__global__ void k_pool(const float* __restrict__ x, const int* __restrict__ batch,
                       float* __restrict__ pooled, int n) {
  int idx = blockIdx.x * 256 + threadIdx.x;
  if (idx < n * HD) {
    int node = idx >> 7;
    atomicAdd(&pooled[batch[node] * HD + (idx & 127)], x[idx]);
  }
}

// Fold edge encoder into msg MLP:  ew[l] = edge_w @ msg_w1[l][256:384,:]  (32x128)
//                                  ebf[l] = msg_b1[l] + edge_b @ msg_w1[l][256:384,:]
__global__ void k_fold_edge(const float* __restrict__ edge_w,   // [32][128]
                            const float* __restrict__ edge_b,   // [128]
                            const float* __restrict__ msg_w1,   // [L][384][128]
                            const float* __restrict__ msg_b1,   // [L][128]
                            float* __restrict__ ew,             // [L][32][128]
                            float* __restrict__ ebf) {          // [L][128]
  int l = blockIdx.x;
  int t = threadIdx.x;
  int j = t & 127;
  int ih = t >> 7;  // 0..1, each covers 16 of the 32 EF rows
  const float* wc = msg_w1 + ((size_t)l * 384 + 256) * HD;  // [128][128]
  float s[16];
#pragma unroll
  for (int ii = 0; ii < 16; ++ii) s[ii] = 0.f;
  for (int k = 0; k < HD; ++k) {
    float wcv = wc[(size_t)k * HD + j];
#pragma unroll
    for (int ii = 0; ii < 16; ++ii)
      s[ii] += edge_w[(ih * 16 + ii) * HD + k] * wcv;
  }
  for (int ii = 0; ii < 16; ++ii)
    ew[((size_t)l * 32 + ih * 16 + ii) * HD + j] = s[ii];
  if (ih == 0) {
    float sb = msg_b1[l * HD + j];
    for (int k = 0; k < HD; ++k) sb += edge_b[k] * wc[(size_t)k * HD + j];
    ebf[l * HD + j] = sb;
  }
}

// ---------------- node encoder: x = nf @ node_w + node_b ----------------
// 64-node x 128-out tile, 256 threads, 4x8 register blocking.
__global__ __launch_bounds__(256) void k_encode(
    const float* __restrict__ nf, const float* __restrict__ w,
    const float* __restrict__ b, float* __restrict__ x, int n) {
  __shared__ float As[32][64];
  __shared__ float Bs[32][128];
  const int t = threadIdx.x;
  const int eg = t & 15, og = t >> 4;
  const int e0 = eg * 4, j0 = og * 8;
  const int n0 = blockIdx.x * 64;

  float acc[4][8];
#pragma unroll
  for (int i = 0; i < 4; ++i)
#pragma unroll
    for (int j = 0; j < 8; ++j) acc[i][j] = 0.f;

  for (int c = 0; c < 2; ++c) {  // K=64 in chunks of 32
    if (c) __syncthreads();
#pragma unroll
    for (int r = 0; r < 2; ++r) {
      int lin = r * 256 + t;
      int e = lin & 63, ks = (lin >> 6) * 4;
      int node = n0 + e; if (node >= n) node = n - 1;
      float4 v = *(const float4*)&nf[(size_t)node * 64 + c * 32 + ks];
      As[ks + 0][e] = v.x; As[ks + 1][e] = v.y; As[ks + 2][e] = v.z; As[ks + 3][e] = v.w;
    }
#pragma unroll
    for (int r = 0; r < 4; ++r) {
      int lin = r * 256 + t;
      int k = lin >> 5, jq = lin & 31;
      *(float4*)&Bs[k][jq * 4] = *(const float4*)&w[(size_t)(c * 32 + k) * HD + jq * 4];
    }
    __syncthreads();
#pragma unroll
    for (int k = 0; k < 32; ++k) {
      float4 a  = *(const float4*)&As[k][e0];
      float4 b0 = *(const float4*)&Bs[k][j0];
      float4 b1 = *(const float4*)&Bs[k][j0 + 4];
      fma_4x8(acc, a, b0, b1);
    }
  }
  float bias[8];
#pragma unroll
  for (int j = 0; j < 8; ++j) bias[j] = b[j0 + j];
#pragma unroll
  for (int ee = 0; ee < 4; ++ee) {
    int node = n0 + e0 + ee;
    if (node < n) {
      float4 o0 = make_float4(acc[ee][0] + bias[0], acc[ee][1] + bias[1],
                              acc[ee][2] + bias[2], acc[ee][3] + bias[3]);
      float4 o1 = make_float4(acc[ee][4] + bias[4], acc[ee][5] + bias[5],
                              acc[ee][6] + bias[6], acc[ee][7] + bias[7]);
      *(float4*)&x[(size_t)node * HD + j0]     = o0;
      *(float4*)&x[(size_t)node * HD + j0 + 4] = o1;
    }
  }
}

// ---------------- fused edge message MLP + scatter-add ----------------
// msg = relu([x[row]|x[col]|ef] @ [W1a;W1b;EW] + b1f) @ W2 + b2 ;  agg[col] += msg
// 64-edge x 128 tile. K1 = 288 (9 chunks of 32), K2 = 128.
__global__ __launch_bounds__(256) void k_edge_msg(
    const float* __restrict__ x, const float* __restrict__ ef,
    const int* __restrict__ rowp, const int* __restrict__ colp,
    const float* __restrict__ w1,    // [384][128] (only rows 0..255 used)
    const float* __restrict__ ew,    // [32][128]
    const float* __restrict__ b1f,   // [128]
    const float* __restrict__ w2,    // [128][128]
    const float* __restrict__ b2,    // [128]
    float* __restrict__ agg, int E) {
  __shared__ float As[32][64];
  __shared__ float Bs[32][128];
  __shared__ float Hs[128][64];
  __shared__ int rls[64], cls[64];
  const int t = threadIdx.x;
  const int eg = t & 15, og = t >> 4;
  const int e0 = eg * 4, j0 = og * 8;
  const int eb = blockIdx.x * 64;

  if (t < 64) {
    int e = eb + t; if (e >= E) e = E - 1;
    rls[t] = rowp[e];
    cls[t] = colp[e];
  }
  __syncthreads();

  float acc[4][8];
#pragma unroll
  for (int i = 0; i < 4; ++i)
#pragma unroll
    for (int j = 0; j < 8; ++j) acc[i][j] = 0.f;

  for (int c = 0; c < 9; ++c) {
    if (c) __syncthreads();
#pragma unroll
    for (int r = 0; r < 2; ++r) {
      int lin = r * 256 + t;
      int e = lin & 63, ks = (lin >> 6) * 4;
      float4 v;
      if (c < 8) {
        int node = (c < 4) ? rls[e] : cls[e];
        v = *(const float4*)&x[(size_t)node * HD + (c & 3) * 32 + ks];
      } else {
        int e2 = eb + e; if (e2 >= E) e2 = E - 1;
        v = *(const float4*)&ef[(size_t)e2 * 32 + ks];
      }
      As[ks + 0][e] = v.x; As[ks + 1][e] = v.y; As[ks + 2][e] = v.z; As[ks + 3][e] = v.w;
    }
    const float* Bsrc = (c < 8) ? (w1 + (size_t)c * 32 * HD) : ew;
#pragma unroll
    for (int r = 0; r < 4; ++r) {
      int lin = r * 256 + t;
      int k = lin >> 5, jq = lin & 31;
      *(float4*)&Bs[k][jq * 4] = *(const float4*)&Bsrc[(size_t)k * HD + jq * 4];
    }
    __syncthreads();
#pragma unroll
    for (int k = 0; k < 32; ++k) {
      float4 a  = *(const float4*)&As[k][e0];
      float4 b0 = *(const float4*)&Bs[k][j0];
      float4 b1 = *(const float4*)&Bs[k][j0 + 4];
      fma_4x8(acc, a, b0, b1);
    }
  }

  // hidden = relu(acc + b1f), transpose-store to Hs[k=j][e]
#pragma unroll
  for (int jj = 0; jj < 8; ++jj) {
    float bb = b1f[j0 + jj];
    float4 h = make_float4(fmaxf(acc[0][jj] + bb, 0.f), fmaxf(acc[1][jj] + bb, 0.f),
                           fmaxf(acc[2][jj] + bb, 0.f), fmaxf(acc[3][jj] + bb, 0.f));
    *(float4*)&Hs[j0 + jj][e0] = h;
  }
  __syncthreads();

#pragma unroll
  for (int i = 0; i < 4; ++i)
#pragma unroll
    for (int j = 0; j < 8; ++j) acc[i][j] = 0.f;

  for (int c = 0; c < 4; ++c) {  // K2 = 128
    if (c) __syncthreads();
#pragma unroll
    for (int r = 0; r < 4; ++r) {
      int lin = r * 256 + t;
      int k = lin >> 5, jq = lin & 31;
      *(float4*)&Bs[k][jq * 4] = *(const float4*)&w2[(size_t)(c * 32 + k) * HD + jq * 4];
    }
    __syncthreads();
#pragma unroll
    for (int k = 0; k < 32; ++k) {
      float4 a  = *(const float4*)&Hs[c * 32 + k][e0];
      float4 b0 = *(const float4*)&Bs[k][j0];
      float4 b1 = *(const float4*)&Bs[k][j0 + 4];
      fma_4x8(acc, a, b0, b1);
    }
  }

  float bias2[8];
#pragma unroll
  for (int jj = 0; jj < 8; ++jj) bias2[jj] = b2[j0 + jj];
#pragma unroll
  for (int ee = 0; ee < 4; ++ee) {
    int e = eb + e0 + ee;
    if (e < E) {
      float* dst = agg + (size_t)cls[e0 + ee] * HD + j0;
#pragma unroll
      for (int jj = 0; jj < 8; ++jj)
        atomicAdd(&dst[jj], acc[ee][jj] + bias2[jj]);
    }
  }
}

// ---------------- node update MLP ----------------
// x_new = relu( relu([x | agg*rdeg] @ upd_w1 + b1) @ upd_w2 + b2 )
__global__ __launch_bounds__(256) void k_update(
    const float* __restrict__ x, const float* __restrict__ agg,
    const float* __restrict__ rdeg,
    const float* __restrict__ w1,    // [256][128]
    const float* __restrict__ b1,    // [128]
    const float* __restrict__ w2,    // [128][128]
    const float* __restrict__ b2,    // [128]
    float* __restrict__ xout, int n) {
  __shared__ float As[32][64];
  __shared__ float Bs[32][128];
  __shared__ float Hs[128][64];
  const int t = threadIdx.x;
  const int eg = t & 15, og = t >> 4;
  const int e0 = eg * 4, j0 = og * 8;
  const int n0 = blockIdx.x * 64;

  float acc[4][8];
#pragma unroll
  for (int i = 0; i < 4; ++i)
#pragma unroll
    for (int j = 0; j < 8; ++j) acc[i][j] = 0.f;

  for (int c = 0; c < 8; ++c) {  // K = 256
    if (c) __syncthreads();
#pragma unroll
    for (int r = 0; r < 2; ++r) {
      int lin = r * 256 + t;
      int e = lin & 63, ks = (lin >> 6) * 4;
      int node = n0 + e; if (node >= n) node = n - 1;
      float4 v;
      if (c < 4) {
        v = *(const float4*)&x[(size_t)node * HD + c * 32 + ks];
      } else {
        v = *(const float4*)&agg[(size_t)node * HD + (c - 4) * 32 + ks];
        float rd = rdeg[node];
        v.x *= rd; v.y *= rd; v.z *= rd; v.w *= rd;
      }
      As[ks + 0][e] = v.x; As[ks + 1][e] = v.y; As[ks + 2][e] = v.z; As[ks + 3][e] = v.w;
    }
#pragma unroll
    for (int r = 0; r < 4; ++r) {
      int lin = r * 256 + t;
      int k = lin >> 5, jq = lin & 31;
      *(float4*)&Bs[k][jq * 4] = *(const float4*)&w1[(size_t)(c * 32 + k) * HD + jq * 4];
    }
    __syncthreads();
#pragma unroll
    for (int k = 0; k < 32; ++k) {
      float4 a  = *(const float4*)&As[k][e0];
      float4 b0 = *(const float4*)&Bs[k][j0];
      float4 b1 = *(const float4*)&Bs[k][j0 + 4];
      fma_4x8(acc, a, b0, b1);
    }
  }

#pragma unroll
  for (int jj = 0; jj < 8; ++jj) {
    float bb = b1[j0 + jj];
    float4 h = make_float4(fmaxf(acc[0][jj] + bb, 0.f), fmaxf(acc[1][jj] + bb, 0.f),
                           fmaxf(acc[2][jj] + bb, 0.f), fmaxf(acc[3][jj] + bb, 0.f));
    *(float4*)&Hs[j0 + jj][e0] = h;
  }
  __syncthreads();

#pragma unroll
  for (int i = 0; i < 4; ++i)
#pragma unroll
    for (int j = 0; j < 8; ++j) acc[i][j] = 0.f;

  for (int c = 0; c < 4; ++c) {
    if (c) __syncthreads();
#pragma unroll
    for (int r = 0; r < 4; ++r) {
      int lin = r * 256 + t;
      int k = lin >> 5, jq = lin & 31;
      *(float4*)&Bs[k][jq * 4] = *(const float4*)&w2[(size_t)(c * 32 + k) * HD + jq * 4];
    }
    __syncthreads();
#pragma unroll
    for (int k = 0; k < 32; ++k) {
      float4 a  = *(const float4*)&Hs[c * 32 + k][e0];
      float4 b0 = *(const float4*)&Bs[k][j0];
      float4 b1 = *(const float4*)&Bs[k][j0 + 4];
      fma_4x8(acc, a, b0, b1);
    }
  }

  float bias2[8];
#pragma unroll
  for (int jj = 0; jj < 8; ++jj) bias2[jj] = b2[j0 + jj];
#pragma unroll
  for (int ee = 0; ee < 4; ++ee) {
    int node = n0 + e0 + ee;
    if (node < n) {
      float4 o0 = make_float4(fmaxf(acc[ee][0] + bias2[0], 0.f), fmaxf(acc[ee][1] + bias2[1], 0.f),
                              fmaxf(acc[ee][2] + bias2[2], 0.f), fmaxf(acc[ee][3] + bias2[3], 0.f));
      float4 o1 = make_float4(fmaxf(acc[ee][4] + bias2[4], 0.f), fmaxf(acc[ee][5] + bias2[5], 0.f),
                              fmaxf(acc[ee][6] + bias2[6], 0.f), fmaxf(acc[ee][7] + bias2[7], 0.f));
      *(float4*)&xout[(size_t)node * HD + j0]     = o0;
      *(float4*)&xout[(size_t)node * HD + j0 + 4] = o1;
    }
  }
}

// ---------------- readout: out = relu(pooled_mean @ ro_w1 + b1) @ ro_w2 + b2 ----------------
__global__ void k_readout(const float* __restrict__ pooled, const float* __restrict__ gcnt,
                          const float* __restrict__ w1, const float* __restrict__ b1,
                          const float* __restrict__ w2, const float* __restrict__ b2,
                          float* __restrict__ out) {
  __shared__ float P[16][128];
  __shared__ float Hh[16][128];
  int t = threadIdx.x;
  int g = t >> 4;
  int jo = (t & 15) * 8;
#pragma unroll
  for (int i = 0; i < 8; ++i) {
    int idx = t * 8 + i;  // 0..2047
    int gg = idx >> 7, j = idx & 127;
    P[gg][j] = pooled[idx] / fmaxf(gcnt[gg], 1.0f);
  }
  __syncthreads();
  float h[8];
#pragma unroll
  for (int jj = 0; jj < 8; ++jj) h[jj] = b1[jo + jj];
  for (int k = 0; k < 128; ++k) {
    float p = P[g][k];
#pragma unroll
    for (int jj = 0; jj < 8; ++jj) h[jj] += p * w1[(size_t)k * HD + jo + jj];
  }
#pragma unroll
  for (int jj = 0; jj < 8; ++jj) Hh[g][jo + jj] = fmaxf(h[jj], 0.f);
  __syncthreads();
  float o[8];
#pragma unroll
  for (int jj = 0; jj < 8; ++jj) o[jj] = b2[jo + jj];
  for (int k = 0; k < 128; ++k) {
    float hv = Hh[g][k];
#pragma unroll
    for (int jj = 0; jj < 8; ++jj) o[jj] += hv * w2[(size_t)k * HD + jo + jj];
  }
#pragma unroll
  for (int jj = 0; jj < 8; ++jj) out[g * HD + jo + jj] = o[jj];
}

// ---------------- launcher ----------------
extern "C" void kernel_launch(void* const* d_in, const int* in_sizes, int n_in,
                              void* d_out, int out_size, void* d_ws, size_t ws_size,
                              hipStream_t stream) {
  const float* nf     = (const float*)d_in[0];
  const int*   ei     = (const int*)d_in[1];
  const float* ef     = (const float*)d_in[2];
  const int*   batch  = (const int*)d_in[3];
  const float* node_w = (const float*)d_in[4];
  const float* node_b = (const float*)d_in[5];
  const float* edge_w = (const float*)d_in[6];
  const float* edge_b = (const float*)d_in[7];
  const float* msg_w1 = (const float*)d_in[8];
  const float* msg_b1 = (const float*)d_in[9];
  const float* msg_w2 = (const float*)d_in[10];
  const float* msg_b2 = (const float*)d_in[11];
  const float* upd_w1 = (const float*)d_in[12];
  const float* upd_b1 = (const float*)d_in[13];
  const float* upd_w2 = (const float*)d_in[14];
  const float* upd_b2 = (const float*)d_in[15];
  const float* ro_w1  = (const float*)d_in[16];
  const float* ro_b1  = (const float*)d_in[17];
  const float* ro_w2  = (const float*)d_in[18];
  const float* ro_b2  = (const float*)d_in[19];

  const int N = in_sizes[3];
  const int E = in_sizes[1] / 2;
  const int* rowp = ei;
  const int* colp = ei + E;

  float* ws = (float*)d_ws;
  float* x0     = ws;  ws += (size_t)N * HD;
  float* x1     = ws;  ws += (size_t)N * HD;
  float* agg    = ws;  ws += (size_t)N * HD;
  float* deg    = ws;  ws += N;           // becomes rdeg in-place
  float* ewf    = ws;  ws += 3 * 32 * HD;
  float* ebf    = ws;  ws += 3 * HD;
  float* pooled = ws;  ws += 16 * HD;
  float* gcnt   = ws;  ws += 16;
  (void)ws_size; (void)n_in; (void)out_size;

  hipMemsetAsync(deg, 0, N * sizeof(float), stream);
  hipMemsetAsync(pooled, 0, (16 * HD + 16) * sizeof(float), stream);  // pooled + gcnt

  k_fold_edge<<<3, 256, 0, stream>>>(edge_w, edge_b, msg_w1, msg_b1, ewf, ebf);
  k_encode<<<(N + 63) / 64, 256, 0, stream>>>(nf, node_w, node_b, x0, N);
  k_deg<<<(E + 255) / 256, 256, 0, stream>>>(colp, deg, E);
  k_rdeg<<<(N + 255) / 256, 256, 0, stream>>>(deg, N);

  float* xc = x0;
  float* xn = x1;
  for (int l = 0; l < 3; ++l) {
    hipMemsetAsync(agg, 0, (size_t)N * HD * sizeof(float), stream);
    k_edge_msg<<<(E + 63) / 64, 256, 0, stream>>>(
        xc, ef, rowp, colp,
        msg_w1 + (size_t)l * 384 * HD, ewf + (size_t)l * 32 * HD, ebf + l * HD,
        msg_w2 + (size_t)l * HD * HD, msg_b2 + l * HD, agg, E);
    k_update<<<(N + 63) / 64, 256, 0, stream>>>(
        xc, agg, deg,
        upd_w1 + (size_t)l * 256 * HD, upd_b1 + l * HD,
        upd_w2 + (size_t)l * HD * HD, upd_b2 + l * HD, xn, N);
    float* tmp = xc; xc = xn; xn = tmp;
  }

  k_gcnt<<<(N + 255) / 256, 256, 0, stream>>>(batch, gcnt, N);
  k_pool<<<((N * HD) + 255) / 256, 256, 0, stream>>>(xc, batch, pooled, N);
  k_readout<<<1, 256, 0, stream>>>(pooled, gcnt, ro_w1, ro_b1, ro_w2, ro_b2, (float*)d_out);
}

// Round 6
// 2128.161 us; speedup vs baseline: 2.4123x; 2.4123x over previous
//
#include <hip/hip_runtime.h>

#define HD 128

__device__ __forceinline__ void fma_4x8(float (&acc)[4][8], float4 a, float4 b0, float4 b1) {
  float av[4] = {a.x, a.y, a.z, a.w};
  float bv[8] = {b0.x, b0.y, b0.z, b0.w, b1.x, b1.y, b1.z, b1.w};
#pragma unroll
  for (int i = 0; i < 4; ++i)
#pragma unroll
    for (int j = 0; j < 8; ++j)
      acc[i][j] += av[i] * bv[j];
}

// ---------------- sorting / degree infrastructure (once per call) ----------------

__global__ void k_cnt(const int* __restrict__ col, int* __restrict__ cnt, int E) {
  int e = blockIdx.x * 256 + threadIdx.x;
  if (e < E) atomicAdd(&cnt[col[e]], 1);
}

__global__ void k_rdeg_flag(const int* __restrict__ cnt, float* __restrict__ rdeg,
                            float* __restrict__ flag, int n) {
  int i = blockIdx.x * 256 + threadIdx.x;
  if (i < n) {
    int c = cnt[i];
    rdeg[i] = 1.0f / fmaxf((float)c, 1.0f);
    flag[i] = (c > 0) ? 1.0f : 0.0f;
  }
}

// single-block exclusive scan of cnt -> cursor (start offsets)
__global__ void k_scan(const int* __restrict__ cnt, int n, int* __restrict__ cursor) {
  __shared__ int ps[1024];
  int tid = threadIdx.x;
  int per = (n + 1023) >> 10;
  int st = tid * per, en = st + per; if (en > n) en = n; if (st > n) st = n;
  int s = 0;
  for (int i = st; i < en; ++i) s += cnt[i];
  ps[tid] = s;
  __syncthreads();
  int tot = s;
  for (int off = 1; off < 1024; off <<= 1) {
    int add = (tid >= off) ? ps[tid - off] : 0;
    __syncthreads();
    ps[tid] += add;
    __syncthreads();
  }
  int run = ps[tid] - tot;  // exclusive prefix
  for (int i = st; i < en; ++i) { cursor[i] = run; run += cnt[i]; }
}

__global__ void k_scatter(const int* __restrict__ rowp, const int* __restrict__ colp,
                          int* __restrict__ cursor, int* __restrict__ rowS,
                          int* __restrict__ colS, int* __restrict__ permS, int E) {
  int e = blockIdx.x * 256 + threadIdx.x;
  if (e < E) {
    int c = colp[e];
    int pos = atomicAdd(&cursor[c], 1);
    rowS[pos] = rowp[e];
    colS[pos] = c;
    permS[pos] = e;
  }
}

// ---------------- misc small kernels ----------------

__global__ void k_gcnt(const int* __restrict__ batch, float* __restrict__ gcnt, int n) {
  int i = blockIdx.x * 256 + threadIdx.x;
  if (i < n) atomicAdd(&gcnt[batch[i]], 1.0f);
}

__global__ void k_pool(const float* __restrict__ x, const int* __restrict__ batch,
                       float* __restrict__ pooled, int n) {
  int idx = blockIdx.x * 256 + threadIdx.x;
  if (idx < n * HD) {
    int node = idx >> 7;
    atomicAdd(&pooled[batch[node] * HD + (idx & 127)], x[idx]);
  }
}

// Fold edge encoder into msg MLP:  ew[l] = edge_w @ msg_w1[l][256:384,:]  (32x128)
//                                  ebf[l] = msg_b1[l] + edge_b @ msg_w1[l][256:384,:]
__global__ void k_fold_edge(const float* __restrict__ edge_w, const float* __restrict__ edge_b,
                            const float* __restrict__ msg_w1, const float* __restrict__ msg_b1,
                            float* __restrict__ ew, float* __restrict__ ebf) {
  int l = blockIdx.x;
  int t = threadIdx.x;
  int j = t & 127;
  int ih = t >> 7;
  const float* wc = msg_w1 + ((size_t)l * 384 + 256) * HD;
  float s[16];
#pragma unroll
  for (int ii = 0; ii < 16; ++ii) s[ii] = 0.f;
  for (int k = 0; k < HD; ++k) {
    float wcv = wc[(size_t)k * HD + j];
#pragma unroll
    for (int ii = 0; ii < 16; ++ii)
      s[ii] += edge_w[(ih * 16 + ii) * HD + k] * wcv;
  }
  for (int ii = 0; ii < 16; ++ii)
    ew[((size_t)l * 32 + ih * 16 + ii) * HD + j] = s[ii];
  if (ih == 0) {
    float sb = msg_b1[l * HD + j];
    for (int k = 0; k < HD; ++k) sb += edge_b[k] * wc[(size_t)k * HD + j];
    ebf[l * HD + j] = sb;
  }
}

// ---------------- node encoder: x = nf @ node_w + node_b  (K=64) ----------------
__global__ __launch_bounds__(256) void k_encode(
    const float* __restrict__ nf, const float* __restrict__ w,
    const float* __restrict__ b, float* __restrict__ x, int n) {
  __shared__ float As[32][64];
  __shared__ float Bs[32][128];
  const int t = threadIdx.x;
  const int eg = t & 15, og = t >> 4;
  const int e0 = eg * 4, j0 = og * 8;
  const int n0 = blockIdx.x * 64;

  float acc[4][8];
#pragma unroll
  for (int i = 0; i < 4; ++i)
#pragma unroll
    for (int j = 0; j < 8; ++j) acc[i][j] = 0.f;

  for (int c = 0; c < 2; ++c) {
    if (c) __syncthreads();
#pragma unroll
    for (int r = 0; r < 2; ++r) {
      int lin = r * 256 + t;
      int e = lin & 63, ks = (lin >> 6) * 4;
      int node = n0 + e; if (node >= n) node = n - 1;
      float4 v = *(const float4*)&nf[(size_t)node * 64 + c * 32 + ks];
      As[ks + 0][e] = v.x; As[ks + 1][e] = v.y; As[ks + 2][e] = v.z; As[ks + 3][e] = v.w;
    }
#pragma unroll
    for (int r = 0; r < 4; ++r) {
      int lin = r * 256 + t;
      int k = lin >> 5, jq = lin & 31;
      *(float4*)&Bs[k][jq * 4] = *(const float4*)&w[(size_t)(c * 32 + k) * HD + jq * 4];
    }
    __syncthreads();
#pragma unroll
    for (int k = 0; k < 32; ++k) {
      float4 a  = *(const float4*)&As[k][e0];
      float4 b0 = *(const float4*)&Bs[k][j0];
      float4 b1 = *(const float4*)&Bs[k][j0 + 4];
      fma_4x8(acc, a, b0, b1);
    }
  }
  float bias[8];
#pragma unroll
  for (int j = 0; j < 8; ++j) bias[j] = b[j0 + j];
#pragma unroll
  for (int ee = 0; ee < 4; ++ee) {
    int node = n0 + e0 + ee;
    if (node < n) {
      float4 o0 = make_float4(acc[ee][0] + bias[0], acc[ee][1] + bias[1],
                              acc[ee][2] + bias[2], acc[ee][3] + bias[3]);
      float4 o1 = make_float4(acc[ee][4] + bias[4], acc[ee][5] + bias[5],
                              acc[ee][6] + bias[6], acc[ee][7] + bias[7]);
      *(float4*)&x[(size_t)node * HD + j0]     = o0;
      *(float4*)&x[(size_t)node * HD + j0 + 4] = o1;
    }
  }
}

// ---------------- generic node GEMM: out = (in * scale?) @ B [+ bias*flag] ----------------
// in [n,128], B [128,128], 64-row tiles, K=128.
__global__ __launch_bounds__(256) void k_ngemm(
    const float* __restrict__ in, const float* __restrict__ B,
    float* __restrict__ out, int n,
    const float* __restrict__ scale,   // per-row or null
    const float* __restrict__ bias,    // per-col or null
    const float* __restrict__ flag) {  // per-row multiplier for bias, or null
  __shared__ float As[32][64];
  __shared__ float Bs[32][128];
  const int t = threadIdx.x;
  const int eg = t & 15, og = t >> 4;
  const int e0 = eg * 4, j0 = og * 8;
  const int n0 = blockIdx.x * 64;

  float acc[4][8];
#pragma unroll
  for (int i = 0; i < 4; ++i)
#pragma unroll
    for (int j = 0; j < 8; ++j) acc[i][j] = 0.f;

  for (int c = 0; c < 4; ++c) {
    if (c) __syncthreads();
#pragma unroll
    for (int r = 0; r < 2; ++r) {
      int lin = r * 256 + t;
      int e = lin & 63, ks = (lin >> 6) * 4;
      int node = n0 + e; if (node >= n) node = n - 1;
      float4 v = *(const float4*)&in[(size_t)node * HD + c * 32 + ks];
      if (scale) {
        float sc = scale[node];
        v.x *= sc; v.y *= sc; v.z *= sc; v.w *= sc;
      }
      As[ks + 0][e] = v.x; As[ks + 1][e] = v.y; As[ks + 2][e] = v.z; As[ks + 3][e] = v.w;
    }
#pragma unroll
    for (int r = 0; r < 4; ++r) {
      int lin = r * 256 + t;
      int k = lin >> 5, jq = lin & 31;
      *(float4*)&Bs[k][jq * 4] = *(const float4*)&B[(size_t)(c * 32 + k) * HD + jq * 4];
    }
    __syncthreads();
#pragma unroll
    for (int k = 0; k < 32; ++k) {
      float4 a  = *(const float4*)&As[k][e0];
      float4 b0 = *(const float4*)&Bs[k][j0];
      float4 b1 = *(const float4*)&Bs[k][j0 + 4];
      fma_4x8(acc, a, b0, b1);
    }
  }
  float bb[8];
#pragma unroll
  for (int j = 0; j < 8; ++j) bb[j] = bias ? bias[j0 + j] : 0.f;
#pragma unroll
  for (int ee = 0; ee < 4; ++ee) {
    int node = n0 + e0 + ee;
    if (node < n) {
      float fl = flag ? flag[node] : 1.0f;
      float4 o0 = make_float4(acc[ee][0] + bb[0] * fl, acc[ee][1] + bb[1] * fl,
                              acc[ee][2] + bb[2] * fl, acc[ee][3] + bb[3] * fl);
      float4 o1 = make_float4(acc[ee][4] + bb[4] * fl, acc[ee][5] + bb[5] * fl,
                              acc[ee][6] + bb[6] * fl, acc[ee][7] + bb[7] * fl);
      *(float4*)&out[(size_t)node * HD + j0]     = o0;
      *(float4*)&out[(size_t)node * HD + j0 + 4] = o1;
    }
  }
}

// ---------------- edge kernel: hidden = relu(xa[row]+xb[col]+ef@EW+b1f); Hsum[col] += hidden ----
// Edges sorted by col. 64 edges/block; thread = 8 consecutive edges x 4 cols; register
// run-reduction over sorted col, atomic flush only on col change (~1.5 flushes / 8 edges).
__global__ __launch_bounds__(256) void k_edge(
    const float* __restrict__ xa, const float* __restrict__ xb,
    const float* __restrict__ ef,
    const int* __restrict__ rowS, const int* __restrict__ colS,
    const int* __restrict__ permS,
    const float* __restrict__ EW,    // [32][128]
    const float* __restrict__ b1f,   // [128]
    float* __restrict__ Hsum, int E) {
  __shared__ float As[32][64];
  __shared__ float Bs[32][128];
  __shared__ int rls[64], cls[64];
  const int t = threadIdx.x;
  const int eg = t & 7, og = t >> 3;   // 8 edge-groups x 32 col-groups
  const int e0 = eg * 8, j0 = og * 4;
  const int eb = blockIdx.x * 64;

  if (t < 64) {
    int e = eb + t; if (e >= E) e = E - 1;
    rls[t] = rowS[e];
    cls[t] = colS[e];
  }
  // stage ef^T for the 64 (permuted) edges
#pragma unroll
  for (int r = 0; r < 2; ++r) {
    int lin = r * 256 + t;
    int e = lin & 63, ks = (lin >> 6) * 4;
    int ee = eb + e; if (ee >= E) ee = E - 1;
    int pe = permS[ee];
    float4 v = *(const float4*)&ef[(size_t)pe * 32 + ks];
    As[ks + 0][e] = v.x; As[ks + 1][e] = v.y; As[ks + 2][e] = v.z; As[ks + 3][e] = v.w;
  }
#pragma unroll
  for (int r = 0; r < 4; ++r) {
    int lin = r * 256 + t;
    int k = lin >> 5, jq = lin & 31;
    *(float4*)&Bs[k][jq * 4] = *(const float4*)&EW[(size_t)k * HD + jq * 4];
  }
  __syncthreads();

  float4 acc[8];
#pragma unroll
  for (int i = 0; i < 8; ++i) acc[i] = make_float4(0.f, 0.f, 0.f, 0.f);
#pragma unroll
  for (int k = 0; k < 32; ++k) {
    float4 b  = *(const float4*)&Bs[k][j0];
    float4 a0 = *(const float4*)&As[k][e0];
    float4 a1 = *(const float4*)&As[k][e0 + 4];
    float av[8] = {a0.x, a0.y, a0.z, a0.w, a1.x, a1.y, a1.z, a1.w};
#pragma unroll
    for (int i = 0; i < 8; ++i) {
      acc[i].x += av[i] * b.x; acc[i].y += av[i] * b.y;
      acc[i].z += av[i] * b.z; acc[i].w += av[i] * b.w;
    }
  }

  float4 bb = *(const float4*)&b1f[j0];
  float4 racc = make_float4(0.f, 0.f, 0.f, 0.f);
  int rcol = cls[e0];
#pragma unroll
  for (int i = 0; i < 8; ++i) {
    int e = e0 + i;
    int c = cls[e];
    if (c != rcol) {
      float* d = &Hsum[(size_t)rcol * HD + j0];
      atomicAdd(d + 0, racc.x); atomicAdd(d + 1, racc.y);
      atomicAdd(d + 2, racc.z); atomicAdd(d + 3, racc.w);
      racc = make_float4(0.f, 0.f, 0.f, 0.f);
      rcol = c;
    }
    if (eb + e < E) {
      float4 va = *(const float4*)&xa[(size_t)rls[e] * HD + j0];
      float4 vb = *(const float4*)&xb[(size_t)c * HD + j0];
      racc.x += fmaxf(acc[i].x + va.x + vb.x + bb.x, 0.f);
      racc.y += fmaxf(acc[i].y + va.y + vb.y + bb.y, 0.f);
      racc.z += fmaxf(acc[i].z + va.z + vb.z + bb.z, 0.f);
      racc.w += fmaxf(acc[i].w + va.w + vb.w + bb.w, 0.f);
    }
  }
  float* d = &Hsum[(size_t)rcol * HD + j0];
  atomicAdd(d + 0, racc.x); atomicAdd(d + 1, racc.y);
  atomicAdd(d + 2, racc.z); atomicAdd(d + 3, racc.w);
}

// ---------------- node update MLP: x_new = relu(relu([x|agg]@U1+b1)@U2+b2) ----------------
__global__ __launch_bounds__(256) void k_update(
    const float* __restrict__ x, const float* __restrict__ agg,
    const float* __restrict__ w1, const float* __restrict__ b1,
    const float* __restrict__ w2, const float* __restrict__ b2,
    float* __restrict__ xout, int n) {
  __shared__ float As[32][64];
  __shared__ float Bs[32][128];
  __shared__ float Hs[128][64];
  const int t = threadIdx.x;
  const int eg = t & 15, og = t >> 4;
  const int e0 = eg * 4, j0 = og * 8;
  const int n0 = blockIdx.x * 64;

  float acc[4][8];
#pragma unroll
  for (int i = 0; i < 4; ++i)
#pragma unroll
    for (int j = 0; j < 8; ++j) acc[i][j] = 0.f;

  for (int c = 0; c < 8; ++c) {
    if (c) __syncthreads();
#pragma unroll
    for (int r = 0; r < 2; ++r) {
      int lin = r * 256 + t;
      int e = lin & 63, ks = (lin >> 6) * 4;
      int node = n0 + e; if (node >= n) node = n - 1;
      float4 v;
      if (c < 4) v = *(const float4*)&x[(size_t)node * HD + c * 32 + ks];
      else       v = *(const float4*)&agg[(size_t)node * HD + (c - 4) * 32 + ks];
      As[ks + 0][e] = v.x; As[ks + 1][e] = v.y; As[ks + 2][e] = v.z; As[ks + 3][e] = v.w;
    }
#pragma unroll
    for (int r = 0; r < 4; ++r) {
      int lin = r * 256 + t;
      int k = lin >> 5, jq = lin & 31;
      *(float4*)&Bs[k][jq * 4] = *(const float4*)&w1[(size_t)(c * 32 + k) * HD + jq * 4];
    }
    __syncthreads();
#pragma unroll
    for (int k = 0; k < 32; ++k) {
      float4 a  = *(const float4*)&As[k][e0];
      float4 b0 = *(const float4*)&Bs[k][j0];
      float4 b1v = *(const float4*)&Bs[k][j0 + 4];
      fma_4x8(acc, a, b0, b1v);
    }
  }

#pragma unroll
  for (int jj = 0; jj < 8; ++jj) {
    float bbv = b1[j0 + jj];
    float4 h = make_float4(fmaxf(acc[0][jj] + bbv, 0.f), fmaxf(acc[1][jj] + bbv, 0.f),
                           fmaxf(acc[2][jj] + bbv, 0.f), fmaxf(acc[3][jj] + bbv, 0.f));
    *(float4*)&Hs[j0 + jj][e0] = h;
  }
  __syncthreads();

#pragma unroll
  for (int i = 0; i < 4; ++i)
#pragma unroll
    for (int j = 0; j < 8; ++j) acc[i][j] = 0.f;

  for (int c = 0; c < 4; ++c) {
    if (c) __syncthreads();
#pragma unroll
    for (int r = 0; r < 4; ++r) {
      int lin = r * 256 + t;
      int k = lin >> 5, jq = lin & 31;
      *(float4*)&Bs[k][jq * 4] = *(const float4*)&w2[(size_t)(c * 32 + k) * HD + jq * 4];
    }
    __syncthreads();
#pragma unroll
    for (int k = 0; k < 32; ++k) {
      float4 a  = *(const float4*)&Hs[c * 32 + k][e0];
      float4 b0 = *(const float4*)&Bs[k][j0];
      float4 b1v = *(const float4*)&Bs[k][j0 + 4];
      fma_4x8(acc, a, b0, b1v);
    }
  }

  float bias2[8];
#pragma unroll
  for (int jj = 0; jj < 8; ++jj) bias2[jj] = b2[j0 + jj];
#pragma unroll
  for (int ee = 0; ee < 4; ++ee) {
    int node = n0 + e0 + ee;
    if (node < n) {
      float4 o0 = make_float4(fmaxf(acc[ee][0] + bias2[0], 0.f), fmaxf(acc[ee][1] + bias2[1], 0.f),
                              fmaxf(acc[ee][2] + bias2[2], 0.f), fmaxf(acc[ee][3] + bias2[3], 0.f));
      float4 o1 = make_float4(fmaxf(acc[ee][4] + bias2[4], 0.f), fmaxf(acc[ee][5] + bias2[5], 0.f),
                              fmaxf(acc[ee][6] + bias2[6], 0.f), fmaxf(acc[ee][7] + bias2[7], 0.f));
      *(float4*)&xout[(size_t)node * HD + j0]     = o0;
      *(float4*)&xout[(size_t)node * HD + j0 + 4] = o1;
    }
  }
}

// ---------------- readout ----------------
__global__ void k_readout(const float* __restrict__ pooled, const float* __restrict__ gcnt,
                          const float* __restrict__ w1, const float* __restrict__ b1,
                          const float* __restrict__ w2, const float* __restrict__ b2,
                          float* __restrict__ out) {
  __shared__ float P[16][128];
  __shared__ float Hh[16][128];
  int t = threadIdx.x;
  int g = t >> 4;
  int jo = (t & 15) * 8;
#pragma unroll
  for (int i = 0; i < 8; ++i) {
    int idx = t * 8 + i;
    int gg = idx >> 7, j = idx & 127;
    P[gg][j] = pooled[idx] / fmaxf(gcnt[gg], 1.0f);
  }
  __syncthreads();
  float h[8];
#pragma unroll
  for (int jj = 0; jj < 8; ++jj) h[jj] = b1[jo + jj];
  for (int k = 0; k < 128; ++k) {
    float p = P[g][k];
#pragma unroll
    for (int jj = 0; jj < 8; ++jj) h[jj] += p * w1[(size_t)k * HD + jo + jj];
  }
#pragma unroll
  for (int jj = 0; jj < 8; ++jj) Hh[g][jo + jj] = fmaxf(h[jj], 0.f);
  __syncthreads();
  float o[8];
#pragma unroll
  for (int jj = 0; jj < 8; ++jj) o[jj] = b2[jo + jj];
  for (int k = 0; k < 128; ++k) {
    float hv = Hh[g][k];
#pragma unroll
    for (int jj = 0; jj < 8; ++jj) o[jj] += hv * w2[(size_t)k * HD + jo + jj];
  }
#pragma unroll
  for (int jj = 0; jj < 8; ++jj) out[g * HD + jo + jj] = o[jj];
}

// ---------------- launcher ----------------
extern "C" void kernel_launch(void* const* d_in, const int* in_sizes, int n_in,
                              void* d_out, int out_size, void* d_ws, size_t ws_size,
                              hipStream_t stream) {
  const float* nf     = (const float*)d_in[0];
  const int*   ei     = (const int*)d_in[1];
  const float* ef     = (const float*)d_in[2];
  const int*   batch  = (const int*)d_in[3];
  const float* node_w = (const float*)d_in[4];
  const float* node_b = (const float*)d_in[5];
  const float* edge_w = (const float*)d_in[6];
  const float* edge_b = (const float*)d_in[7];
  const float* msg_w1 = (const float*)d_in[8];
  const float* msg_b1 = (const float*)d_in[9];
  const float* msg_w2 = (const float*)d_in[10];
  const float* msg_b2 = (const float*)d_in[11];
  const float* upd_w1 = (const float*)d_in[12];
  const float* upd_b1 = (const float*)d_in[13];
  const float* upd_w2 = (const float*)d_in[14];
  const float* upd_b2 = (const float*)d_in[15];
  const float* ro_w1  = (const float*)d_in[16];
  const float* ro_b1  = (const float*)d_in[17];
  const float* ro_w2  = (const float*)d_in[18];
  const float* ro_b2  = (const float*)d_in[19];

  const int N = in_sizes[3];
  const int E = in_sizes[1] / 2;
  const int* rowp = ei;
  const int* colp = ei + E;
  const size_t NH = (size_t)N * HD;

  float* w = (float*)d_ws;
  float* P0 = w; w += NH;
  float* P1 = w; w += NH;
  float* P2 = w; w += NH;
  float* P3 = w; w += NH;
  float* rdeg = w; w += N;
  float* flag = w; w += N;
  float* ewf  = w; w += 3 * 32 * HD;
  float* ebf  = w; w += 3 * HD;
  float* pooled = w; w += 16 * HD;
  float* gcnt = w; w += 16;
  int* cnt    = (int*)w; w += N;
  int* cursor = (int*)w; w += N;
  int* rowS   = (int*)w; w += E;
  int* colS   = (int*)w; w += E;
  int* permS  = (int*)w; w += E;
  (void)ws_size; (void)n_in; (void)out_size;

  hipMemsetAsync(cnt, 0, N * sizeof(int), stream);
  hipMemsetAsync(pooled, 0, (16 * HD + 16) * sizeof(float), stream);  // pooled + gcnt

  k_fold_edge<<<3, 256, 0, stream>>>(edge_w, edge_b, msg_w1, msg_b1, ewf, ebf);
  k_encode<<<(N + 63) / 64, 256, 0, stream>>>(nf, node_w, node_b, P0, N);
  k_cnt<<<(E + 255) / 256, 256, 0, stream>>>(colp, cnt, E);
  k_rdeg_flag<<<(N + 255) / 256, 256, 0, stream>>>(cnt, rdeg, flag, N);
  k_scan<<<1, 1024, 0, stream>>>(cnt, N, cursor);
  k_scatter<<<(E + 255) / 256, 256, 0, stream>>>(rowp, colp, cursor, rowS, colS, permS, E);

  float* X = P0;   // current features
  float* A = P1;   // xa, later agg
  float* B = P2;   // xb, later x_next
  float* H = P3;   // Hsum
  const int ngrid = (N + 63) / 64;
  for (int l = 0; l < 3; ++l) {
    hipMemsetAsync(H, 0, NH * sizeof(float), stream);
    const float* W1a = msg_w1 + (size_t)l * 384 * HD;
    const float* W1b = W1a + (size_t)HD * HD;
    k_ngemm<<<ngrid, 256, 0, stream>>>(X, W1a, A, N, nullptr, nullptr, nullptr);  // xa
    k_ngemm<<<ngrid, 256, 0, stream>>>(X, W1b, B, N, nullptr, nullptr, nullptr);  // xb
    k_edge<<<(E + 63) / 64, 256, 0, stream>>>(A, B, ef, rowS, colS, permS,
                                              ewf + (size_t)l * 32 * HD, ebf + l * HD, H, E);
    // agg = (Hsum * rdeg) @ msg_w2 + msg_b2 * (deg>0)   -> into A (xa dead)
    k_ngemm<<<ngrid, 256, 0, stream>>>(H, msg_w2 + (size_t)l * HD * HD, A, N,
                                       rdeg, msg_b2 + l * HD, flag);
    k_update<<<ngrid, 256, 0, stream>>>(X, A,
        upd_w1 + (size_t)l * 256 * HD, upd_b1 + l * HD,
        upd_w2 + (size_t)l * HD * HD, upd_b2 + l * HD, B, N);
    float* tmp = X; X = B; B = tmp;  // A and H reused next layer
  }

  k_gcnt<<<(N + 255) / 256, 256, 0, stream>>>(batch, gcnt, N);
  k_pool<<<((N * HD) + 255) / 256, 256, 0, stream>>>(X, batch, pooled, N);
  k_readout<<<1, 256, 0, stream>>>(pooled, gcnt, ro_w1, ro_b1, ro_w2, ro_b2, (float*)d_out);
}

// Round 7
// 1677.854 us; speedup vs baseline: 3.0598x; 1.2684x over previous
//
#include <hip/hip_runtime.h>

#define HD 128

__device__ __forceinline__ void fma_4x8(float (&acc)[4][8], float4 a, float4 b0, float4 b1) {
  float av[4] = {a.x, a.y, a.z, a.w};
  float bv[8] = {b0.x, b0.y, b0.z, b0.w, b1.x, b1.y, b1.z, b1.w};
#pragma unroll
  for (int i = 0; i < 4; ++i)
#pragma unroll
    for (int j = 0; j < 8; ++j)
      acc[i][j] += av[i] * bv[j];
}

// ---------------- CSR build (once per call) ----------------

__global__ void k_cnt(const int* __restrict__ col, int* __restrict__ cnt, int E) {
  int e = blockIdx.x * 256 + threadIdx.x;
  if (e < E) atomicAdd(&cnt[col[e]], 1);
}

__global__ void k_rdeg_flag(const int* __restrict__ cnt, float* __restrict__ rdeg,
                            float* __restrict__ flag, int n) {
  int i = blockIdx.x * 256 + threadIdx.x;
  if (i < n) {
    int c = cnt[i];
    rdeg[i] = 1.0f / fmaxf((float)c, 1.0f);
    flag[i] = (c > 0) ? 1.0f : 0.0f;
  }
}

// single-block exclusive scan of cnt -> cursor (mutable) and rowptr (CSR, n+1)
__global__ void k_scan(const int* __restrict__ cnt, int n,
                       int* __restrict__ cursor, int* __restrict__ rowptr) {
  __shared__ int ps[1024];
  int tid = threadIdx.x;
  int per = (n + 1023) >> 10;
  int st = tid * per, en = st + per; if (en > n) en = n; if (st > n) st = n;
  int s = 0;
  for (int i = st; i < en; ++i) s += cnt[i];
  ps[tid] = s;
  __syncthreads();
  int tot = s;
  for (int off = 1; off < 1024; off <<= 1) {
    int add = (tid >= off) ? ps[tid - off] : 0;
    __syncthreads();
    ps[tid] += add;
    __syncthreads();
  }
  int run = ps[tid] - tot;  // exclusive prefix
  for (int i = st; i < en; ++i) { cursor[i] = run; rowptr[i] = run; run += cnt[i]; }
  if (tid == 1023) rowptr[n] = run;  // == E
}

__global__ void k_scatter(const int* __restrict__ rowp, const int* __restrict__ colp,
                          int* __restrict__ cursor, int* __restrict__ rowS,
                          int* __restrict__ permS, int E) {
  int e = blockIdx.x * 256 + threadIdx.x;
  if (e < E) {
    int pos = atomicAdd(&cursor[colp[e]], 1);
    rowS[pos] = rowp[e];
    permS[pos] = e;
  }
}

// ---------------- misc small kernels ----------------

__global__ void k_gcnt(const int* __restrict__ batch, float* __restrict__ gcnt, int n) {
  int i = blockIdx.x * 256 + threadIdx.x;
  if (i < n) atomicAdd(&gcnt[batch[i]], 1.0f);
}

__global__ void k_pool(const float* __restrict__ x, const int* __restrict__ batch,
                       float* __restrict__ pooled, int n) {
  int idx = blockIdx.x * 256 + threadIdx.x;
  if (idx < n * HD) {
    int node = idx >> 7;
    atomicAdd(&pooled[batch[node] * HD + (idx & 127)], x[idx]);
  }
}

// Fold edge encoder into msg MLP:  ew[l] = edge_w @ msg_w1[l][256:384,:]  (32x128)
//                                  ebf[l] = msg_b1[l] + edge_b @ msg_w1[l][256:384,:]
__global__ void k_fold_edge(const float* __restrict__ edge_w, const float* __restrict__ edge_b,
                            const float* __restrict__ msg_w1, const float* __restrict__ msg_b1,
                            float* __restrict__ ew, float* __restrict__ ebf) {
  int l = blockIdx.x;
  int t = threadIdx.x;
  int j = t & 127;
  int ih = t >> 7;
  const float* wc = msg_w1 + ((size_t)l * 384 + 256) * HD;
  float s[16];
#pragma unroll
  for (int ii = 0; ii < 16; ++ii) s[ii] = 0.f;
  for (int k = 0; k < HD; ++k) {
    float wcv = wc[(size_t)k * HD + j];
#pragma unroll
    for (int ii = 0; ii < 16; ++ii)
      s[ii] += edge_w[(ih * 16 + ii) * HD + k] * wcv;
  }
  for (int ii = 0; ii < 16; ++ii)
    ew[((size_t)l * 32 + ih * 16 + ii) * HD + j] = s[ii];
  if (ih == 0) {
    float sb = msg_b1[l * HD + j];
    for (int k = 0; k < HD; ++k) sb += edge_b[k] * wc[(size_t)k * HD + j];
    ebf[l * HD + j] = sb;
  }
}

// ---------------- node encoder: x = nf @ node_w + node_b  (K=64) ----------------
__global__ __launch_bounds__(256) void k_encode(
    const float* __restrict__ nf, const float* __restrict__ w,
    const float* __restrict__ b, float* __restrict__ x, int n) {
  __shared__ float As[32][64];
  __shared__ float Bs[32][128];
  const int t = threadIdx.x;
  const int eg = t & 15, og = t >> 4;
  const int e0 = eg * 4, j0 = og * 8;
  const int n0 = blockIdx.x * 64;

  float acc[4][8];
#pragma unroll
  for (int i = 0; i < 4; ++i)
#pragma unroll
    for (int j = 0; j < 8; ++j) acc[i][j] = 0.f;

  for (int c = 0; c < 2; ++c) {
    if (c) __syncthreads();
#pragma unroll
    for (int r = 0; r < 2; ++r) {
      int lin = r * 256 + t;
      int e = lin & 63, ks = (lin >> 6) * 4;
      int node = n0 + e; if (node >= n) node = n - 1;
      float4 v = *(const float4*)&nf[(size_t)node * 64 + c * 32 + ks];
      As[ks + 0][e] = v.x; As[ks + 1][e] = v.y; As[ks + 2][e] = v.z; As[ks + 3][e] = v.w;
    }
#pragma unroll
    for (int r = 0; r < 4; ++r) {
      int lin = r * 256 + t;
      int k = lin >> 5, jq = lin & 31;
      *(float4*)&Bs[k][jq * 4] = *(const float4*)&w[(size_t)(c * 32 + k) * HD + jq * 4];
    }
    __syncthreads();
#pragma unroll
    for (int k = 0; k < 32; ++k) {
      float4 a  = *(const float4*)&As[k][e0];
      float4 b0 = *(const float4*)&Bs[k][j0];
      float4 b1 = *(const float4*)&Bs[k][j0 + 4];
      fma_4x8(acc, a, b0, b1);
    }
  }
  float bias[8];
#pragma unroll
  for (int j = 0; j < 8; ++j) bias[j] = b[j0 + j];
#pragma unroll
  for (int ee = 0; ee < 4; ++ee) {
    int node = n0 + e0 + ee;
    if (node < n) {
      float4 o0 = make_float4(acc[ee][0] + bias[0], acc[ee][1] + bias[1],
                              acc[ee][2] + bias[2], acc[ee][3] + bias[3]);
      float4 o1 = make_float4(acc[ee][4] + bias[4], acc[ee][5] + bias[5],
                              acc[ee][6] + bias[6], acc[ee][7] + bias[7]);
      *(float4*)&x[(size_t)node * HD + j0]     = o0;
      *(float4*)&x[(size_t)node * HD + j0 + 4] = o1;
    }
  }
}

// ---------------- dual node GEMM: out1 = X@B1,  out2 = X@B2 + bias2 ----------------
__global__ __launch_bounds__(256) void k_ngemm2(
    const float* __restrict__ X, const float* __restrict__ B1,
    const float* __restrict__ B2, const float* __restrict__ bias2,
    float* __restrict__ out1, float* __restrict__ out2, int n) {
  __shared__ float As[32][64];
  __shared__ float Bs1[32][128];
  __shared__ float Bs2[32][128];
  const int t = threadIdx.x;
  const int eg = t & 15, og = t >> 4;
  const int e0 = eg * 4, j0 = og * 8;
  const int n0 = blockIdx.x * 64;

  float acc1[4][8], acc2[4][8];
#pragma unroll
  for (int i = 0; i < 4; ++i)
#pragma unroll
    for (int j = 0; j < 8; ++j) { acc1[i][j] = 0.f; acc2[i][j] = 0.f; }

  for (int c = 0; c < 4; ++c) {
    if (c) __syncthreads();
#pragma unroll
    for (int r = 0; r < 2; ++r) {
      int lin = r * 256 + t;
      int e = lin & 63, ks = (lin >> 6) * 4;
      int node = n0 + e; if (node >= n) node = n - 1;
      float4 v = *(const float4*)&X[(size_t)node * HD + c * 32 + ks];
      As[ks + 0][e] = v.x; As[ks + 1][e] = v.y; As[ks + 2][e] = v.z; As[ks + 3][e] = v.w;
    }
#pragma unroll
    for (int r = 0; r < 4; ++r) {
      int lin = r * 256 + t;
      int k = lin >> 5, jq = lin & 31;
      *(float4*)&Bs1[k][jq * 4] = *(const float4*)&B1[(size_t)(c * 32 + k) * HD + jq * 4];
      *(float4*)&Bs2[k][jq * 4] = *(const float4*)&B2[(size_t)(c * 32 + k) * HD + jq * 4];
    }
    __syncthreads();
#pragma unroll
    for (int k = 0; k < 32; ++k) {
      float4 a = *(const float4*)&As[k][e0];
      fma_4x8(acc1, a, *(const float4*)&Bs1[k][j0], *(const float4*)&Bs1[k][j0 + 4]);
      fma_4x8(acc2, a, *(const float4*)&Bs2[k][j0], *(const float4*)&Bs2[k][j0 + 4]);
    }
  }
  float bb[8];
#pragma unroll
  for (int j = 0; j < 8; ++j) bb[j] = bias2[j0 + j];
#pragma unroll
  for (int ee = 0; ee < 4; ++ee) {
    int node = n0 + e0 + ee;
    if (node < n) {
      *(float4*)&out1[(size_t)node * HD + j0] =
          make_float4(acc1[ee][0], acc1[ee][1], acc1[ee][2], acc1[ee][3]);
      *(float4*)&out1[(size_t)node * HD + j0 + 4] =
          make_float4(acc1[ee][4], acc1[ee][5], acc1[ee][6], acc1[ee][7]);
      *(float4*)&out2[(size_t)node * HD + j0] =
          make_float4(acc2[ee][0] + bb[0], acc2[ee][1] + bb[1],
                      acc2[ee][2] + bb[2], acc2[ee][3] + bb[3]);
      *(float4*)&out2[(size_t)node * HD + j0 + 4] =
          make_float4(acc2[ee][4] + bb[4], acc2[ee][5] + bb[5],
                      acc2[ee][6] + bb[6], acc2[ee][7] + bb[7]);
    }
  }
}

// ---------------- pull-CSR edge kernel (no atomics) ----------------
// Hs[c] = rdeg[c] * sum_{e in in(c)} relu( xa[rowS[e]] + xbb[c] + ef[permS[e]] @ EW )
// One wave per node; lane owns 2 columns; EW held in 64 VGPRs/lane.
__global__ __launch_bounds__(256) void k_edge_pull(
    const float* __restrict__ xa, const float* __restrict__ xbb,
    const float* __restrict__ ef,
    const int* __restrict__ rowS, const int* __restrict__ permS,
    const int* __restrict__ rowptr,
    const float* __restrict__ EW,    // [32][128]
    const float* __restrict__ rdeg,
    float* __restrict__ Hs, int n) {
  const int lane = threadIdx.x & 63;
  const int node = blockIdx.x * 4 + (threadIdx.x >> 6);
  float2 ew[32];
#pragma unroll
  for (int k = 0; k < 32; ++k)
    ew[k] = *(const float2*)&EW[k * HD + lane * 2];
  if (node >= n) return;
  const int s = rowptr[node], en = rowptr[node + 1];
  const float2 xb2 = *(const float2*)&xbb[(size_t)node * HD + lane * 2];
  float accx = 0.f, accy = 0.f;
  for (int e = s; e < en; ++e) {
    const int r = rowS[e];
    const int pe = permS[e];
    const float4* efp = (const float4*)&ef[(size_t)pe * 32];
    float4 q0 = efp[0], q1 = efp[1], q2 = efp[2], q3 = efp[3];
    float4 q4 = efp[4], q5 = efp[5], q6 = efp[6], q7 = efp[7];
    const float2 xa2 = *(const float2*)&xa[(size_t)r * HD + lane * 2];
    float efv[32] = {q0.x, q0.y, q0.z, q0.w, q1.x, q1.y, q1.z, q1.w,
                     q2.x, q2.y, q2.z, q2.w, q3.x, q3.y, q3.z, q3.w,
                     q4.x, q4.y, q4.z, q4.w, q5.x, q5.y, q5.z, q5.w,
                     q6.x, q6.y, q6.z, q6.w, q7.x, q7.y, q7.z, q7.w};
    float etx = 0.f, ety = 0.f;
#pragma unroll
    for (int k = 0; k < 32; ++k) {
      etx += efv[k] * ew[k].x;
      ety += efv[k] * ew[k].y;
    }
    accx += fmaxf(xa2.x + xb2.x + etx, 0.f);
    accy += fmaxf(xa2.y + xb2.y + ety, 0.f);
  }
  const float rd = rdeg[node];
  float2 o; o.x = accx * rd; o.y = accy * rd;
  *(float2*)&Hs[(size_t)node * HD + lane * 2] = o;
}

// ---------------- fused: agg = Hs@W2 + b2*flag ; x_new = relu(relu([X|agg]@U1+b1)@U2+b2) ----
__global__ __launch_bounds__(256) void k_upd_fused(
    const float* __restrict__ X, const float* __restrict__ Hs,
    const float* __restrict__ w2m, const float* __restrict__ b2m,
    const float* __restrict__ flag,
    const float* __restrict__ u1, const float* __restrict__ ub1,
    const float* __restrict__ u2, const float* __restrict__ ub2,
    float* __restrict__ xout, int n) {
  __shared__ float As[32][64];
  __shared__ float Bs[32][128];
  __shared__ float Hl[128][64];   // agg^T, then hidden^T
  const int t = threadIdx.x;
  const int eg = t & 15, og = t >> 4;
  const int e0 = eg * 4, j0 = og * 8;
  const int n0 = blockIdx.x * 64;

  float acc[4][8];
#pragma unroll
  for (int i = 0; i < 4; ++i)
#pragma unroll
    for (int j = 0; j < 8; ++j) acc[i][j] = 0.f;

  // Phase A: agg^T = (Hs@w2m + b2m*flag)^T  -> Hl
  for (int c = 0; c < 4; ++c) {
    if (c) __syncthreads();
#pragma unroll
    for (int r = 0; r < 2; ++r) {
      int lin = r * 256 + t;
      int e = lin & 63, ks = (lin >> 6) * 4;
      int node = n0 + e; if (node >= n) node = n - 1;
      float4 v = *(const float4*)&Hs[(size_t)node * HD + c * 32 + ks];
      As[ks + 0][e] = v.x; As[ks + 1][e] = v.y; As[ks + 2][e] = v.z; As[ks + 3][e] = v.w;
    }
#pragma unroll
    for (int r = 0; r < 4; ++r) {
      int lin = r * 256 + t;
      int k = lin >> 5, jq = lin & 31;
      *(float4*)&Bs[k][jq * 4] = *(const float4*)&w2m[(size_t)(c * 32 + k) * HD + jq * 4];
    }
    __syncthreads();
#pragma unroll
    for (int k = 0; k < 32; ++k) {
      float4 a = *(const float4*)&As[k][e0];
      fma_4x8(acc, a, *(const float4*)&Bs[k][j0], *(const float4*)&Bs[k][j0 + 4]);
    }
  }
  {
    float fl[4];
#pragma unroll
    for (int ee = 0; ee < 4; ++ee) {
      int node = n0 + e0 + ee; if (node >= n) node = n - 1;
      fl[ee] = flag[node];
    }
#pragma unroll
    for (int jj = 0; jj < 8; ++jj) {
      float bb = b2m[j0 + jj];
      float4 h = make_float4(acc[0][jj] + bb * fl[0], acc[1][jj] + bb * fl[1],
                             acc[2][jj] + bb * fl[2], acc[3][jj] + bb * fl[3]);
      *(float4*)&Hl[j0 + jj][e0] = h;
    }
  }
  __syncthreads();  // Hl ready; also As/Bs free to restage

  // Phase B: K=256 over [X | Hl]
#pragma unroll
  for (int i = 0; i < 4; ++i)
#pragma unroll
    for (int j = 0; j < 8; ++j) acc[i][j] = 0.f;
  for (int c = 0; c < 8; ++c) {
    if (c) __syncthreads();
    if (c < 4) {
#pragma unroll
      for (int r = 0; r < 2; ++r) {
        int lin = r * 256 + t;
        int e = lin & 63, ks = (lin >> 6) * 4;
        int node = n0 + e; if (node >= n) node = n - 1;
        float4 v = *(const float4*)&X[(size_t)node * HD + c * 32 + ks];
        As[ks + 0][e] = v.x; As[ks + 1][e] = v.y; As[ks + 2][e] = v.z; As[ks + 3][e] = v.w;
      }
    }
#pragma unroll
    for (int r = 0; r < 4; ++r) {
      int lin = r * 256 + t;
      int k = lin >> 5, jq = lin & 31;
      *(float4*)&Bs[k][jq * 4] = *(const float4*)&u1[(size_t)(c * 32 + k) * HD + jq * 4];
    }
    __syncthreads();
    if (c < 4) {
#pragma unroll
      for (int k = 0; k < 32; ++k) {
        float4 a = *(const float4*)&As[k][e0];
        fma_4x8(acc, a, *(const float4*)&Bs[k][j0], *(const float4*)&Bs[k][j0 + 4]);
      }
    } else {
#pragma unroll
      for (int k = 0; k < 32; ++k) {
        float4 a = *(const float4*)&Hl[(c - 4) * 32 + k][e0];
        fma_4x8(acc, a, *(const float4*)&Bs[k][j0], *(const float4*)&Bs[k][j0 + 4]);
      }
    }
  }
  __syncthreads();  // all reads of Hl done
#pragma unroll
  for (int jj = 0; jj < 8; ++jj) {
    float bb = ub1[j0 + jj];
    float4 h = make_float4(fmaxf(acc[0][jj] + bb, 0.f), fmaxf(acc[1][jj] + bb, 0.f),
                           fmaxf(acc[2][jj] + bb, 0.f), fmaxf(acc[3][jj] + bb, 0.f));
    *(float4*)&Hl[j0 + jj][e0] = h;
  }
  __syncthreads();  // hidden ready; Bs free

  // Phase C: K=128 from Hl
#pragma unroll
  for (int i = 0; i < 4; ++i)
#pragma unroll
    for (int j = 0; j < 8; ++j) acc[i][j] = 0.f;
  for (int c = 0; c < 4; ++c) {
    if (c) __syncthreads();
#pragma unroll
    for (int r = 0; r < 4; ++r) {
      int lin = r * 256 + t;
      int k = lin >> 5, jq = lin & 31;
      *(float4*)&Bs[k][jq * 4] = *(const float4*)&u2[(size_t)(c * 32 + k) * HD + jq * 4];
    }
    __syncthreads();
#pragma unroll
    for (int k = 0; k < 32; ++k) {
      float4 a = *(const float4*)&Hl[c * 32 + k][e0];
      fma_4x8(acc, a, *(const float4*)&Bs[k][j0], *(const float4*)&Bs[k][j0 + 4]);
    }
  }
  float bias2[8];
#pragma unroll
  for (int jj = 0; jj < 8; ++jj) bias2[jj] = ub2[j0 + jj];
#pragma unroll
  for (int ee = 0; ee < 4; ++ee) {
    int node = n0 + e0 + ee;
    if (node < n) {
      float4 o0 = make_float4(fmaxf(acc[ee][0] + bias2[0], 0.f), fmaxf(acc[ee][1] + bias2[1], 0.f),
                              fmaxf(acc[ee][2] + bias2[2], 0.f), fmaxf(acc[ee][3] + bias2[3], 0.f));
      float4 o1 = make_float4(fmaxf(acc[ee][4] + bias2[4], 0.f), fmaxf(acc[ee][5] + bias2[5], 0.f),
                              fmaxf(acc[ee][6] + bias2[6], 0.f), fmaxf(acc[ee][7] + bias2[7], 0.f));
      *(float4*)&xout[(size_t)node * HD + j0]     = o0;
      *(float4*)&xout[(size_t)node * HD + j0 + 4] = o1;
    }
  }
}

// ---------------- readout ----------------
__global__ void k_readout(const float* __restrict__ pooled, const float* __restrict__ gcnt,
                          const float* __restrict__ w1, const float* __restrict__ b1,
                          const float* __restrict__ w2, const float* __restrict__ b2,
                          float* __restrict__ out) {
  __shared__ float P[16][128];
  __shared__ float Hh[16][128];
  int t = threadIdx.x;
  int g = t >> 4;
  int jo = (t & 15) * 8;
#pragma unroll
  for (int i = 0; i < 8; ++i) {
    int idx = t * 8 + i;
    int gg = idx >> 7, j = idx & 127;
    P[gg][j] = pooled[idx] / fmaxf(gcnt[gg], 1.0f);
  }
  __syncthreads();
  float h[8];
#pragma unroll
  for (int jj = 0; jj < 8; ++jj) h[jj] = b1[jo + jj];
  for (int k = 0; k < 128; ++k) {
    float p = P[g][k];
#pragma unroll
    for (int jj = 0; jj < 8; ++jj) h[jj] += p * w1[(size_t)k * HD + jo + jj];
  }
#pragma unroll
  for (int jj = 0; jj < 8; ++jj) Hh[g][jo + jj] = fmaxf(h[jj], 0.f);
  __syncthreads();
  float o[8];
#pragma unroll
  for (int jj = 0; jj < 8; ++jj) o[jj] = b2[jo + jj];
  for (int k = 0; k < 128; ++k) {
    float hv = Hh[g][k];
#pragma unroll
    for (int jj = 0; jj < 8; ++jj) o[jj] += hv * w2[(size_t)k * HD + jo + jj];
  }
#pragma unroll
  for (int jj = 0; jj < 8; ++jj) out[g * HD + jo + jj] = o[jj];
}

// ---------------- launcher ----------------
extern "C" void kernel_launch(void* const* d_in, const int* in_sizes, int n_in,
                              void* d_out, int out_size, void* d_ws, size_t ws_size,
                              hipStream_t stream) {
  const float* nf     = (const float*)d_in[0];
  const int*   ei     = (const int*)d_in[1];
  const float* ef     = (const float*)d_in[2];
  const int*   batch  = (const int*)d_in[3];
  const float* node_w = (const float*)d_in[4];
  const float* node_b = (const float*)d_in[5];
  const float* edge_w = (const float*)d_in[6];
  const float* edge_b = (const float*)d_in[7];
  const float* msg_w1 = (const float*)d_in[8];
  const float* msg_b1 = (const float*)d_in[9];
  const float* msg_w2 = (const float*)d_in[10];
  const float* msg_b2 = (const float*)d_in[11];
  const float* upd_w1 = (const float*)d_in[12];
  const float* upd_b1 = (const float*)d_in[13];
  const float* upd_w2 = (const float*)d_in[14];
  const float* upd_b2 = (const float*)d_in[15];
  const float* ro_w1  = (const float*)d_in[16];
  const float* ro_b1  = (const float*)d_in[17];
  const float* ro_w2  = (const float*)d_in[18];
  const float* ro_b2  = (const float*)d_in[19];

  const int N = in_sizes[3];
  const int E = in_sizes[1] / 2;
  const int* rowp = ei;
  const int* colp = ei + E;
  const size_t NH = (size_t)N * HD;

  float* w = (float*)d_ws;
  float* P0 = w; w += NH;   // X (even layers)
  float* P1 = w; w += NH;   // xa
  float* P2 = w; w += NH;   // xbb
  float* P3 = w; w += NH;   // Hs
  float* P4 = w; w += NH;   // X (odd layers)
  float* rdeg = w; w += N;
  float* flag = w; w += N;
  float* ewf  = w; w += 3 * 32 * HD;
  float* ebf  = w; w += 3 * HD;
  float* pooled = w; w += 16 * HD;
  float* gcnt = w; w += 16;
  int* cnt    = (int*)w; w += N;
  int* cursor = (int*)w; w += N;
  int* rowptr = (int*)w; w += (N + 1);
  int* rowS   = (int*)w; w += E;
  int* permS  = (int*)w; w += E;
  (void)ws_size; (void)n_in; (void)out_size;

  hipMemsetAsync(cnt, 0, N * sizeof(int), stream);
  hipMemsetAsync(pooled, 0, (16 * HD + 16) * sizeof(float), stream);  // pooled + gcnt

  k_fold_edge<<<3, 256, 0, stream>>>(edge_w, edge_b, msg_w1, msg_b1, ewf, ebf);
  k_encode<<<(N + 63) / 64, 256, 0, stream>>>(nf, node_w, node_b, P0, N);
  k_cnt<<<(E + 255) / 256, 256, 0, stream>>>(colp, cnt, E);
  k_rdeg_flag<<<(N + 255) / 256, 256, 0, stream>>>(cnt, rdeg, flag, N);
  k_scan<<<1, 1024, 0, stream>>>(cnt, N, cursor, rowptr);
  k_scatter<<<(E + 255) / 256, 256, 0, stream>>>(rowp, colp, cursor, rowS, permS, E);

  const int ngrid = (N + 63) / 64;
  float* X = P0;
  float* Xn = P4;
  for (int l = 0; l < 3; ++l) {
    const float* W1a = msg_w1 + (size_t)l * 384 * HD;
    const float* W1b = W1a + (size_t)HD * HD;
    k_ngemm2<<<ngrid, 256, 0, stream>>>(X, W1a, W1b, ebf + l * HD, P1, P2, N);
    k_edge_pull<<<(N + 3) / 4, 256, 0, stream>>>(P1, P2, ef, rowS, permS, rowptr,
                                                 ewf + (size_t)l * 32 * HD, rdeg, P3, N);
    k_upd_fused<<<ngrid, 256, 0, stream>>>(X, P3,
        msg_w2 + (size_t)l * HD * HD, msg_b2 + l * HD, flag,
        upd_w1 + (size_t)l * 256 * HD, upd_b1 + l * HD,
        upd_w2 + (size_t)l * HD * HD, upd_b2 + l * HD, Xn, N);
    float* tmp = X; X = Xn; Xn = tmp;
  }

  k_gcnt<<<(N + 255) / 256, 256, 0, stream>>>(batch, gcnt, N);
  k_pool<<<((N * HD) + 255) / 256, 256, 0, stream>>>(X, batch, pooled, N);
  k_readout<<<1, 256, 0, stream>>>(pooled, gcnt, ro_w1, ro_b1, ro_w2, ro_b2, (float*)d_out);
}

// Round 8
// 1301.913 us; speedup vs baseline: 3.9433x; 1.2888x over previous
//
#include <hip/hip_runtime.h>

#define HD 128

__device__ __forceinline__ void fma_4x8(float (&acc)[4][8], float4 a, float4 b0, float4 b1) {
  float av[4] = {a.x, a.y, a.z, a.w};
  float bv[8] = {b0.x, b0.y, b0.z, b0.w, b1.x, b1.y, b1.z, b1.w};
#pragma unroll
  for (int i = 0; i < 4; ++i)
#pragma unroll
    for (int j = 0; j < 8; ++j)
      acc[i][j] += av[i] * bv[j];
}

// ---------------- CSR build (once per call) ----------------

__global__ void k_cnt(const int* __restrict__ col, int* __restrict__ cnt, int E) {
  int e = blockIdx.x * 256 + threadIdx.x;
  if (e < E) atomicAdd(&cnt[col[e]], 1);
}

__global__ void k_rdeg_flag(const int* __restrict__ cnt, float* __restrict__ rdeg,
                            float* __restrict__ flag, int n) {
  int i = blockIdx.x * 256 + threadIdx.x;
  if (i < n) {
    int c = cnt[i];
    rdeg[i] = 1.0f / fmaxf((float)c, 1.0f);
    flag[i] = (c > 0) ? 1.0f : 0.0f;
  }
}

// single-block exclusive scan of cnt -> cursor (mutable) and rowptr (CSR, n+1)
__global__ void k_scan(const int* __restrict__ cnt, int n,
                       int* __restrict__ cursor, int* __restrict__ rowptr) {
  __shared__ int ps[1024];
  int tid = threadIdx.x;
  int per = (n + 1023) >> 10;
  int st = tid * per, en = st + per; if (en > n) en = n; if (st > n) st = n;
  int s = 0;
  for (int i = st; i < en; ++i) s += cnt[i];
  ps[tid] = s;
  __syncthreads();
  int tot = s;
  for (int off = 1; off < 1024; off <<= 1) {
    int add = (tid >= off) ? ps[tid - off] : 0;
    __syncthreads();
    ps[tid] += add;
    __syncthreads();
  }
  int run = ps[tid] - tot;  // exclusive prefix
  for (int i = st; i < en; ++i) { cursor[i] = run; rowptr[i] = run; run += cnt[i]; }
  if (tid == 1023) rowptr[n] = run;  // == E
}

__global__ void k_scatter(const int* __restrict__ rowp, const int* __restrict__ colp,
                          int* __restrict__ cursor, int* __restrict__ rowS,
                          int* __restrict__ permS, int E) {
  int e = blockIdx.x * 256 + threadIdx.x;
  if (e < E) {
    int pos = atomicAdd(&cursor[colp[e]], 1);
    rowS[pos] = rowp[e];
    permS[pos] = e;
  }
}

// ---------------- batched pooling via sorted-batch boundaries (no atomics) ----------------

// gstart[g] = lower_bound(batch, g) for g in [0,16]; batch is sorted.
__global__ void k_bounds(const int* __restrict__ batch, int* __restrict__ gstart, int n) {
  int g = threadIdx.x;
  if (g > 16) return;
  int lo = 0, hi = n;
  while (lo < hi) {
    int mid = (lo + hi) >> 1;
    if (batch[mid] < g) lo = mid + 1; else hi = mid;
  }
  gstart[g] = lo;
}

// pooled[g][cols] = mean over contiguous node range [gstart[g], gstart[g+1])
// grid = 16 graphs x 4 col-chunks; block 256 = 8 row-groups x 32 cols.
__global__ void k_pool_seg(const float* __restrict__ x, const int* __restrict__ gstart,
                           float* __restrict__ pooled) {
  int b = blockIdx.x;
  int g = b >> 2, cg = b & 3;
  int t = threadIdx.x;
  int jc = t & 31;
  int rg = t >> 5;
  int s = gstart[g], e = gstart[g + 1];
  float acc = 0.f;
  for (int r = s + rg; r < e; r += 8)
    acc += x[(size_t)r * HD + cg * 32 + jc];
  __shared__ float red[8][32];
  red[rg][jc] = acc;
  __syncthreads();
  if (rg == 0) {
    float sum = 0.f;
#pragma unroll
    for (int i = 0; i < 8; ++i) sum += red[i][jc];
    float cntf = (float)(e - s);
    pooled[g * HD + cg * 32 + jc] = sum / fmaxf(cntf, 1.0f);
  }
}

// Fold edge encoder into msg MLP:  ew[l] = edge_w @ msg_w1[l][256:384,:]  (32x128)
//                                  ebf[l] = msg_b1[l] + edge_b @ msg_w1[l][256:384,:]
__global__ void k_fold_edge(const float* __restrict__ edge_w, const float* __restrict__ edge_b,
                            const float* __restrict__ msg_w1, const float* __restrict__ msg_b1,
                            float* __restrict__ ew, float* __restrict__ ebf) {
  int l = blockIdx.x;
  int t = threadIdx.x;
  int j = t & 127;
  int ih = t >> 7;
  const float* wc = msg_w1 + ((size_t)l * 384 + 256) * HD;
  float s[16];
#pragma unroll
  for (int ii = 0; ii < 16; ++ii) s[ii] = 0.f;
  for (int k = 0; k < HD; ++k) {
    float wcv = wc[(size_t)k * HD + j];
#pragma unroll
    for (int ii = 0; ii < 16; ++ii)
      s[ii] += edge_w[(ih * 16 + ii) * HD + k] * wcv;
  }
  for (int ii = 0; ii < 16; ++ii)
    ew[((size_t)l * 32 + ih * 16 + ii) * HD + j] = s[ii];
  if (ih == 0) {
    float sb = msg_b1[l * HD + j];
    for (int k = 0; k < HD; ++k) sb += edge_b[k] * wc[(size_t)k * HD + j];
    ebf[l * HD + j] = sb;
  }
}

// ---------------- node encoder: x = nf @ node_w + node_b  (K=64) ----------------
__global__ __launch_bounds__(256) void k_encode(
    const float* __restrict__ nf, const float* __restrict__ w,
    const float* __restrict__ b, float* __restrict__ x, int n) {
  __shared__ float As[32][64];
  __shared__ float Bs[32][128];
  const int t = threadIdx.x;
  const int eg = t & 15, og = t >> 4;
  const int e0 = eg * 4, j0 = og * 8;
  const int n0 = blockIdx.x * 64;

  float acc[4][8];
#pragma unroll
  for (int i = 0; i < 4; ++i)
#pragma unroll
    for (int j = 0; j < 8; ++j) acc[i][j] = 0.f;

  for (int c = 0; c < 2; ++c) {
    if (c) __syncthreads();
#pragma unroll
    for (int r = 0; r < 2; ++r) {
      int lin = r * 256 + t;
      int e = lin & 63, ks = (lin >> 6) * 4;
      int node = n0 + e; if (node >= n) node = n - 1;
      float4 v = *(const float4*)&nf[(size_t)node * 64 + c * 32 + ks];
      As[ks + 0][e] = v.x; As[ks + 1][e] = v.y; As[ks + 2][e] = v.z; As[ks + 3][e] = v.w;
    }
#pragma unroll
    for (int r = 0; r < 4; ++r) {
      int lin = r * 256 + t;
      int k = lin >> 5, jq = lin & 31;
      *(float4*)&Bs[k][jq * 4] = *(const float4*)&w[(size_t)(c * 32 + k) * HD + jq * 4];
    }
    __syncthreads();
#pragma unroll
    for (int k = 0; k < 32; ++k) {
      float4 a  = *(const float4*)&As[k][e0];
      float4 b0 = *(const float4*)&Bs[k][j0];
      float4 b1 = *(const float4*)&Bs[k][j0 + 4];
      fma_4x8(acc, a, b0, b1);
    }
  }
  float bias[8];
#pragma unroll
  for (int j = 0; j < 8; ++j) bias[j] = b[j0 + j];
#pragma unroll
  for (int ee = 0; ee < 4; ++ee) {
    int node = n0 + e0 + ee;
    if (node < n) {
      float4 o0 = make_float4(acc[ee][0] + bias[0], acc[ee][1] + bias[1],
                              acc[ee][2] + bias[2], acc[ee][3] + bias[3]);
      float4 o1 = make_float4(acc[ee][4] + bias[4], acc[ee][5] + bias[5],
                              acc[ee][6] + bias[6], acc[ee][7] + bias[7]);
      *(float4*)&x[(size_t)node * HD + j0]     = o0;
      *(float4*)&x[(size_t)node * HD + j0 + 4] = o1;
    }
  }
}

// ---------------- dual node GEMM: out1 = X@B1,  out2 = X@B2 + bias2 ----------------
__global__ __launch_bounds__(256) void k_ngemm2(
    const float* __restrict__ X, const float* __restrict__ B1,
    const float* __restrict__ B2, const float* __restrict__ bias2,
    float* __restrict__ out1, float* __restrict__ out2, int n) {
  __shared__ float As[32][64];
  __shared__ float Bs1[32][128];
  __shared__ float Bs2[32][128];
  const int t = threadIdx.x;
  const int eg = t & 15, og = t >> 4;
  const int e0 = eg * 4, j0 = og * 8;
  const int n0 = blockIdx.x * 64;

  float acc1[4][8], acc2[4][8];
#pragma unroll
  for (int i = 0; i < 4; ++i)
#pragma unroll
    for (int j = 0; j < 8; ++j) { acc1[i][j] = 0.f; acc2[i][j] = 0.f; }

  for (int c = 0; c < 4; ++c) {
    if (c) __syncthreads();
#pragma unroll
    for (int r = 0; r < 2; ++r) {
      int lin = r * 256 + t;
      int e = lin & 63, ks = (lin >> 6) * 4;
      int node = n0 + e; if (node >= n) node = n - 1;
      float4 v = *(const float4*)&X[(size_t)node * HD + c * 32 + ks];
      As[ks + 0][e] = v.x; As[ks + 1][e] = v.y; As[ks + 2][e] = v.z; As[ks + 3][e] = v.w;
    }
#pragma unroll
    for (int r = 0; r < 4; ++r) {
      int lin = r * 256 + t;
      int k = lin >> 5, jq = lin & 31;
      *(float4*)&Bs1[k][jq * 4] = *(const float4*)&B1[(size_t)(c * 32 + k) * HD + jq * 4];
      *(float4*)&Bs2[k][jq * 4] = *(const float4*)&B2[(size_t)(c * 32 + k) * HD + jq * 4];
    }
    __syncthreads();
#pragma unroll
    for (int k = 0; k < 32; ++k) {
      float4 a = *(const float4*)&As[k][e0];
      fma_4x8(acc1, a, *(const float4*)&Bs1[k][j0], *(const float4*)&Bs1[k][j0 + 4]);
      fma_4x8(acc2, a, *(const float4*)&Bs2[k][j0], *(const float4*)&Bs2[k][j0 + 4]);
    }
  }
  float bb[8];
#pragma unroll
  for (int j = 0; j < 8; ++j) bb[j] = bias2[j0 + j];
#pragma unroll
  for (int ee = 0; ee < 4; ++ee) {
    int node = n0 + e0 + ee;
    if (node < n) {
      *(float4*)&out1[(size_t)node * HD + j0] =
          make_float4(acc1[ee][0], acc1[ee][1], acc1[ee][2], acc1[ee][3]);
      *(float4*)&out1[(size_t)node * HD + j0 + 4] =
          make_float4(acc1[ee][4], acc1[ee][5], acc1[ee][6], acc1[ee][7]);
      *(float4*)&out2[(size_t)node * HD + j0] =
          make_float4(acc2[ee][0] + bb[0], acc2[ee][1] + bb[1],
                      acc2[ee][2] + bb[2], acc2[ee][3] + bb[3]);
      *(float4*)&out2[(size_t)node * HD + j0 + 4] =
          make_float4(acc2[ee][4] + bb[4], acc2[ee][5] + bb[5],
                      acc2[ee][6] + bb[6], acc2[ee][7] + bb[7]);
    }
  }
}

// ---------------- pull-CSR edge kernel (no atomics) ----------------
// Hs[c] = rdeg[c] * sum_{e in in(c)} relu( xa[rowS[e]] + xbb[c] + ef[permS[e]] @ EW )
// One wave per node; lane owns 2 columns; EW held in 64 VGPRs/lane.
__global__ __launch_bounds__(256) void k_edge_pull(
    const float* __restrict__ xa, const float* __restrict__ xbb,
    const float* __restrict__ ef,
    const int* __restrict__ rowS, const int* __restrict__ permS,
    const int* __restrict__ rowptr,
    const float* __restrict__ EW,    // [32][128]
    const float* __restrict__ rdeg,
    float* __restrict__ Hs, int n) {
  const int lane = threadIdx.x & 63;
  const int node = blockIdx.x * 4 + (threadIdx.x >> 6);
  float2 ew[32];
#pragma unroll
  for (int k = 0; k < 32; ++k)
    ew[k] = *(const float2*)&EW[k * HD + lane * 2];
  if (node >= n) return;
  const int s = rowptr[node], en = rowptr[node + 1];
  const float2 xb2 = *(const float2*)&xbb[(size_t)node * HD + lane * 2];
  float accx = 0.f, accy = 0.f;
  for (int e = s; e < en; ++e) {
    const int r = rowS[e];
    const int pe = permS[e];
    const float4* efp = (const float4*)&ef[(size_t)pe * 32];
    float4 q0 = efp[0], q1 = efp[1], q2 = efp[2], q3 = efp[3];
    float4 q4 = efp[4], q5 = efp[5], q6 = efp[6], q7 = efp[7];
    const float2 xa2 = *(const float2*)&xa[(size_t)r * HD + lane * 2];
    float efv[32] = {q0.x, q0.y, q0.z, q0.w, q1.x, q1.y, q1.z, q1.w,
                     q2.x, q2.y, q2.z, q2.w, q3.x, q3.y, q3.z, q3.w,
                     q4.x, q4.y, q4.z, q4.w, q5.x, q5.y, q5.z, q5.w,
                     q6.x, q6.y, q6.z, q6.w, q7.x, q7.y, q7.z, q7.w};
    float etx = 0.f, ety = 0.f;
#pragma unroll
    for (int k = 0; k < 32; ++k) {
      etx += efv[k] * ew[k].x;
      ety += efv[k] * ew[k].y;
    }
    accx += fmaxf(xa2.x + xb2.x + etx, 0.f);
    accy += fmaxf(xa2.y + xb2.y + ety, 0.f);
  }
  const float rd = rdeg[node];
  float2 o; o.x = accx * rd; o.y = accy * rd;
  *(float2*)&Hs[(size_t)node * HD + lane * 2] = o;
}

// ---------------- fused: agg = Hs@W2 + b2*flag ; x_new = relu(relu([X|agg]@U1+b1)@U2+b2) ----
__global__ __launch_bounds__(256) void k_upd_fused(
    const float* __restrict__ X, const float* __restrict__ Hs,
    const float* __restrict__ w2m, const float* __restrict__ b2m,
    const float* __restrict__ flag,
    const float* __restrict__ u1, const float* __restrict__ ub1,
    const float* __restrict__ u2, const float* __restrict__ ub2,
    float* __restrict__ xout, int n) {
  __shared__ float As[32][64];
  __shared__ float Bs[32][128];
  __shared__ float Hl[128][64];   // agg^T, then hidden^T
  const int t = threadIdx.x;
  const int eg = t & 15, og = t >> 4;
  const int e0 = eg * 4, j0 = og * 8;
  const int n0 = blockIdx.x * 64;

  float acc[4][8];
#pragma unroll
  for (int i = 0; i < 4; ++i)
#pragma unroll
    for (int j = 0; j < 8; ++j) acc[i][j] = 0.f;

  // Phase A: agg^T = (Hs@w2m + b2m*flag)^T  -> Hl
  for (int c = 0; c < 4; ++c) {
    if (c) __syncthreads();
#pragma unroll
    for (int r = 0; r < 2; ++r) {
      int lin = r * 256 + t;
      int e = lin & 63, ks = (lin >> 6) * 4;
      int node = n0 + e; if (node >= n) node = n - 1;
      float4 v = *(const float4*)&Hs[(size_t)node * HD + c * 32 + ks];
      As[ks + 0][e] = v.x; As[ks + 1][e] = v.y; As[ks + 2][e] = v.z; As[ks + 3][e] = v.w;
    }
#pragma unroll
    for (int r = 0; r < 4; ++r) {
      int lin = r * 256 + t;
      int k = lin >> 5, jq = lin & 31;
      *(float4*)&Bs[k][jq * 4] = *(const float4*)&w2m[(size_t)(c * 32 + k) * HD + jq * 4];
    }
    __syncthreads();
#pragma unroll
    for (int k = 0; k < 32; ++k) {
      float4 a = *(const float4*)&As[k][e0];
      fma_4x8(acc, a, *(const float4*)&Bs[k][j0], *(const float4*)&Bs[k][j0 + 4]);
    }
  }
  {
    float fl[4];
#pragma unroll
    for (int ee = 0; ee < 4; ++ee) {
      int node = n0 + e0 + ee; if (node >= n) node = n - 1;
      fl[ee] = flag[node];
    }
#pragma unroll
    for (int jj = 0; jj < 8; ++jj) {
      float bb = b2m[j0 + jj];
      float4 h = make_float4(acc[0][jj] + bb * fl[0], acc[1][jj] + bb * fl[1],
                             acc[2][jj] + bb * fl[2], acc[3][jj] + bb * fl[3]);
      *(float4*)&Hl[j0 + jj][e0] = h;
    }
  }
  __syncthreads();  // Hl ready; also As/Bs free to restage

  // Phase B: K=256 over [X | Hl]
#pragma unroll
  for (int i = 0; i < 4; ++i)
#pragma unroll
    for (int j = 0; j < 8; ++j) acc[i][j] = 0.f;
  for (int c = 0; c < 8; ++c) {
    if (c) __syncthreads();
    if (c < 4) {
#pragma unroll
      for (int r = 0; r < 2; ++r) {
        int lin = r * 256 + t;
        int e = lin & 63, ks = (lin >> 6) * 4;
        int node = n0 + e; if (node >= n) node = n - 1;
        float4 v = *(const float4*)&X[(size_t)node * HD + c * 32 + ks];
        As[ks + 0][e] = v.x; As[ks + 1][e] = v.y; As[ks + 2][e] = v.z; As[ks + 3][e] = v.w;
      }
    }
#pragma unroll
    for (int r = 0; r < 4; ++r) {
      int lin = r * 256 + t;
      int k = lin >> 5, jq = lin & 31;
      *(float4*)&Bs[k][jq * 4] = *(const float4*)&u1[(size_t)(c * 32 + k) * HD + jq * 4];
    }
    __syncthreads();
    if (c < 4) {
#pragma unroll
      for (int k = 0; k < 32; ++k) {
        float4 a = *(const float4*)&As[k][e0];
        fma_4x8(acc, a, *(const float4*)&Bs[k][j0], *(const float4*)&Bs[k][j0 + 4]);
      }
    } else {
#pragma unroll
      for (int k = 0; k < 32; ++k) {
        float4 a = *(const float4*)&Hl[(c - 4) * 32 + k][e0];
        fma_4x8(acc, a, *(const float4*)&Bs[k][j0], *(const float4*)&Bs[k][j0 + 4]);
      }
    }
  }
  __syncthreads();  // all reads of Hl done
#pragma unroll
  for (int jj = 0; jj < 8; ++jj) {
    float bb = ub1[j0 + jj];
    float4 h = make_float4(fmaxf(acc[0][jj] + bb, 0.f), fmaxf(acc[1][jj] + bb, 0.f),
                           fmaxf(acc[2][jj] + bb, 0.f), fmaxf(acc[3][jj] + bb, 0.f));
    *(float4*)&Hl[j0 + jj][e0] = h;
  }
  __syncthreads();  // hidden ready; Bs free

  // Phase C: K=128 from Hl
#pragma unroll
  for (int i = 0; i < 4; ++i)
#pragma unroll
    for (int j = 0; j < 8; ++j) acc[i][j] = 0.f;
  for (int c = 0; c < 4; ++c) {
    if (c) __syncthreads();
#pragma unroll
    for (int r = 0; r < 4; ++r) {
      int lin = r * 256 + t;
      int k = lin >> 5, jq = lin & 31;
      *(float4*)&Bs[k][jq * 4] = *(const float4*)&u2[(size_t)(c * 32 + k) * HD + jq * 4];
    }
    __syncthreads();
#pragma unroll
    for (int k = 0; k < 32; ++k) {
      float4 a = *(const float4*)&Hl[c * 32 + k][e0];
      fma_4x8(acc, a, *(const float4*)&Bs[k][j0], *(const float4*)&Bs[k][j0 + 4]);
    }
  }
  float bias2[8];
#pragma unroll
  for (int jj = 0; jj < 8; ++jj) bias2[jj] = ub2[j0 + jj];
#pragma unroll
  for (int ee = 0; ee < 4; ++ee) {
    int node = n0 + e0 + ee;
    if (node < n) {
      float4 o0 = make_float4(fmaxf(acc[ee][0] + bias2[0], 0.f), fmaxf(acc[ee][1] + bias2[1], 0.f),
                              fmaxf(acc[ee][2] + bias2[2], 0.f), fmaxf(acc[ee][3] + bias2[3], 0.f));
      float4 o1 = make_float4(fmaxf(acc[ee][4] + bias2[4], 0.f), fmaxf(acc[ee][5] + bias2[5], 0.f),
                              fmaxf(acc[ee][6] + bias2[6], 0.f), fmaxf(acc[ee][7] + bias2[7], 0.f));
      *(float4*)&xout[(size_t)node * HD + j0]     = o0;
      *(float4*)&xout[(size_t)node * HD + j0 + 4] = o1;
    }
  }
}

// ---------------- readout: out = relu(pooled @ ro_w1 + b1) @ ro_w2 + b2 ----------------
__global__ void k_readout(const float* __restrict__ pooled,
                          const float* __restrict__ w1, const float* __restrict__ b1,
                          const float* __restrict__ w2, const float* __restrict__ b2,
                          float* __restrict__ out) {
  __shared__ float P[16][128];
  __shared__ float Hh[16][128];
  int t = threadIdx.x;
  int g = t >> 4;
  int jo = (t & 15) * 8;
#pragma unroll
  for (int i = 0; i < 8; ++i) {
    int idx = t * 8 + i;
    int gg = idx >> 7, j = idx & 127;
    P[gg][j] = pooled[idx];
  }
  __syncthreads();
  float h[8];
#pragma unroll
  for (int jj = 0; jj < 8; ++jj) h[jj] = b1[jo + jj];
  for (int k = 0; k < 128; ++k) {
    float p = P[g][k];
#pragma unroll
    for (int jj = 0; jj < 8; ++jj) h[jj] += p * w1[(size_t)k * HD + jo + jj];
  }
#pragma unroll
  for (int jj = 0; jj < 8; ++jj) Hh[g][jo + jj] = fmaxf(h[jj], 0.f);
  __syncthreads();
  float o[8];
#pragma unroll
  for (int jj = 0; jj < 8; ++jj) o[jj] = b2[jo + jj];
  for (int k = 0; k < 128; ++k) {
    float hv = Hh[g][k];
#pragma unroll
    for (int jj = 0; jj < 8; ++jj) o[jj] += hv * w2[(size_t)k * HD + jo + jj];
  }
#pragma unroll
  for (int jj = 0; jj < 8; ++jj) out[g * HD + jo + jj] = o[jj];
}

// ---------------- launcher ----------------
extern "C" void kernel_launch(void* const* d_in, const int* in_sizes, int n_in,
                              void* d_out, int out_size, void* d_ws, size_t ws_size,
                              hipStream_t stream) {
  const float* nf     = (const float*)d_in[0];
  const int*   ei     = (const int*)d_in[1];
  const float* ef     = (const float*)d_in[2];
  const int*   batch  = (const int*)d_in[3];
  const float* node_w = (const float*)d_in[4];
  const float* node_b = (const float*)d_in[5];
  const float* edge_w = (const float*)d_in[6];
  const float* edge_b = (const float*)d_in[7];
  const float* msg_w1 = (const float*)d_in[8];
  const float* msg_b1 = (const float*)d_in[9];
  const float* msg_w2 = (const float*)d_in[10];
  const float* msg_b2 = (const float*)d_in[11];
  const float* upd_w1 = (const float*)d_in[12];
  const float* upd_b1 = (const float*)d_in[13];
  const float* upd_w2 = (const float*)d_in[14];
  const float* upd_b2 = (const float*)d_in[15];
  const float* ro_w1  = (const float*)d_in[16];
  const float* ro_b1  = (const float*)d_in[17];
  const float* ro_w2  = (const float*)d_in[18];
  const float* ro_b2  = (const float*)d_in[19];

  const int N = in_sizes[3];
  const int E = in_sizes[1] / 2;
  const int* rowp = ei;
  const int* colp = ei + E;
  const size_t NH = (size_t)N * HD;

  float* w = (float*)d_ws;
  float* P0 = w; w += NH;   // X (even layers)
  float* P1 = w; w += NH;   // xa
  float* P2 = w; w += NH;   // xbb
  float* P3 = w; w += NH;   // Hs
  float* P4 = w; w += NH;   // X (odd layers)
  float* rdeg = w; w += N;
  float* flag = w; w += N;
  float* ewf  = w; w += 3 * 32 * HD;
  float* ebf  = w; w += 3 * HD;
  float* pooled = w; w += 16 * HD;
  int* cnt    = (int*)w; w += N;
  int* cursor = (int*)w; w += N;
  int* rowptr = (int*)w; w += (N + 1);
  int* gstart = (int*)w; w += 17;
  int* rowS   = (int*)w; w += E;
  int* permS  = (int*)w; w += E;
  (void)ws_size; (void)n_in; (void)out_size;

  hipMemsetAsync(cnt, 0, N * sizeof(int), stream);

  k_fold_edge<<<3, 256, 0, stream>>>(edge_w, edge_b, msg_w1, msg_b1, ewf, ebf);
  k_encode<<<(N + 63) / 64, 256, 0, stream>>>(nf, node_w, node_b, P0, N);
  k_cnt<<<(E + 255) / 256, 256, 0, stream>>>(colp, cnt, E);
  k_rdeg_flag<<<(N + 255) / 256, 256, 0, stream>>>(cnt, rdeg, flag, N);
  k_scan<<<1, 1024, 0, stream>>>(cnt, N, cursor, rowptr);
  k_scatter<<<(E + 255) / 256, 256, 0, stream>>>(rowp, colp, cursor, rowS, permS, E);
  k_bounds<<<1, 64, 0, stream>>>(batch, gstart, N);

  const int ngrid = (N + 63) / 64;
  float* X = P0;
  float* Xn = P4;
  for (int l = 0; l < 3; ++l) {
    const float* W1a = msg_w1 + (size_t)l * 384 * HD;
    const float* W1b = W1a + (size_t)HD * HD;
    k_ngemm2<<<ngrid, 256, 0, stream>>>(X, W1a, W1b, ebf + l * HD, P1, P2, N);
    k_edge_pull<<<(N + 3) / 4, 256, 0, stream>>>(P1, P2, ef, rowS, permS, rowptr,
                                                 ewf + (size_t)l * 32 * HD, rdeg, P3, N);
    k_upd_fused<<<ngrid, 256, 0, stream>>>(X, P3,
        msg_w2 + (size_t)l * HD * HD, msg_b2 + l * HD, flag,
        upd_w1 + (size_t)l * 256 * HD, upd_b1 + l * HD,
        upd_w2 + (size_t)l * HD * HD, upd_b2 + l * HD, Xn, N);
    float* tmp = X; X = Xn; Xn = tmp;
  }

  k_pool_seg<<<64, 256, 0, stream>>>(X, gstart, pooled);
  k_readout<<<1, 256, 0, stream>>>(pooled, ro_w1, ro_b1, ro_w2, ro_b2, (float*)d_out);
}

// Round 9
// 1216.119 us; speedup vs baseline: 4.2215x; 1.0705x over previous
//
#include <hip/hip_runtime.h>

#define HD 128

__device__ __forceinline__ void fma_4x8(float (&acc)[4][8], float4 a, float4 b0, float4 b1) {
  float av[4] = {a.x, a.y, a.z, a.w};
  float bv[8] = {b0.x, b0.y, b0.z, b0.w, b1.x, b1.y, b1.z, b1.w};
#pragma unroll
  for (int i = 0; i < 4; ++i)
#pragma unroll
    for (int j = 0; j < 8; ++j)
      acc[i][j] += av[i] * bv[j];
}

// ---------------- CSR build (once per call) ----------------

__global__ void k_cnt(const int* __restrict__ col, int* __restrict__ cnt, int E) {
  int e = blockIdx.x * 256 + threadIdx.x;
  if (e < E) atomicAdd(&cnt[col[e]], 1);
}

__global__ void k_rdeg_flag(const int* __restrict__ cnt, float* __restrict__ rdeg,
                            float* __restrict__ flag, int n) {
  int i = blockIdx.x * 256 + threadIdx.x;
  if (i < n) {
    int c = cnt[i];
    rdeg[i] = 1.0f / fmaxf((float)c, 1.0f);
    flag[i] = (c > 0) ? 1.0f : 0.0f;
  }
}

// single-block exclusive scan of cnt -> cursor (mutable) and rowptr (CSR, n+1)
__global__ void k_scan(const int* __restrict__ cnt, int n,
                       int* __restrict__ cursor, int* __restrict__ rowptr) {
  __shared__ int ps[1024];
  int tid = threadIdx.x;
  int per = (n + 1023) >> 10;
  int st = tid * per, en = st + per; if (en > n) en = n; if (st > n) st = n;
  int s = 0;
  for (int i = st; i < en; ++i) s += cnt[i];
  ps[tid] = s;
  __syncthreads();
  int tot = s;
  for (int off = 1; off < 1024; off <<= 1) {
    int add = (tid >= off) ? ps[tid - off] : 0;
    __syncthreads();
    ps[tid] += add;
    __syncthreads();
  }
  int run = ps[tid] - tot;  // exclusive prefix
  for (int i = st; i < en; ++i) { cursor[i] = run; rowptr[i] = run; run += cnt[i]; }
  if (tid == 1023) rowptr[n] = run;  // == E
}

__global__ void k_scatter(const int* __restrict__ rowp, const int* __restrict__ colp,
                          int* __restrict__ cursor, int* __restrict__ rowS,
                          int* __restrict__ permS, int E) {
  int e = blockIdx.x * 256 + threadIdx.x;
  if (e < E) {
    int pos = atomicAdd(&cursor[colp[e]], 1);
    rowS[pos] = rowp[e];
    permS[pos] = e;
  }
}

// gather ef rows into sorted-edge order (layer-invariant): efS[e] = ef[permS[e]]
__global__ void k_permute_ef(const float* __restrict__ ef, const int* __restrict__ permS,
                             float* __restrict__ efS, int E) {
  int idx = blockIdx.x * 256 + threadIdx.x;  // float4 index
  if (idx < E * 8) {
    int e = idx >> 3, q = idx & 7;
    ((float4*)efS)[idx] = ((const float4*)ef)[(size_t)permS[e] * 8 + q];
  }
}

// ---------------- batched pooling via sorted-batch boundaries (no atomics) ----------------

__global__ void k_bounds(const int* __restrict__ batch, int* __restrict__ gstart, int n) {
  int g = threadIdx.x;
  if (g > 16) return;
  int lo = 0, hi = n;
  while (lo < hi) {
    int mid = (lo + hi) >> 1;
    if (batch[mid] < g) lo = mid + 1; else hi = mid;
  }
  gstart[g] = lo;
}

__global__ void k_pool_seg(const float* __restrict__ x, const int* __restrict__ gstart,
                           float* __restrict__ pooled) {
  int b = blockIdx.x;
  int g = b >> 2, cg = b & 3;
  int t = threadIdx.x;
  int jc = t & 31;
  int rg = t >> 5;
  int s = gstart[g], e = gstart[g + 1];
  float acc = 0.f;
  for (int r = s + rg; r < e; r += 8)
    acc += x[(size_t)r * HD + cg * 32 + jc];
  __shared__ float red[8][32];
  red[rg][jc] = acc;
  __syncthreads();
  if (rg == 0) {
    float sum = 0.f;
#pragma unroll
    for (int i = 0; i < 8; ++i) sum += red[i][jc];
    float cntf = (float)(e - s);
    pooled[g * HD + cg * 32 + jc] = sum / fmaxf(cntf, 1.0f);
  }
}

// Fold edge encoder into msg MLP:  ew[l] = edge_w @ msg_w1[l][256:384,:]  (32x128)
//                                  ebf[l] = msg_b1[l] + edge_b @ msg_w1[l][256:384,:]
__global__ void k_fold_edge(const float* __restrict__ edge_w, const float* __restrict__ edge_b,
                            const float* __restrict__ msg_w1, const float* __restrict__ msg_b1,
                            float* __restrict__ ew, float* __restrict__ ebf) {
  int l = blockIdx.x;
  int t = threadIdx.x;
  int j = t & 127;
  int ih = t >> 7;
  const float* wc = msg_w1 + ((size_t)l * 384 + 256) * HD;
  float s[16];
#pragma unroll
  for (int ii = 0; ii < 16; ++ii) s[ii] = 0.f;
  for (int k = 0; k < HD; ++k) {
    float wcv = wc[(size_t)k * HD + j];
#pragma unroll
    for (int ii = 0; ii < 16; ++ii)
      s[ii] += edge_w[(ih * 16 + ii) * HD + k] * wcv;
  }
  for (int ii = 0; ii < 16; ++ii)
    ew[((size_t)l * 32 + ih * 16 + ii) * HD + j] = s[ii];
  if (ih == 0) {
    float sb = msg_b1[l * HD + j];
    for (int k = 0; k < HD; ++k) sb += edge_b[k] * wc[(size_t)k * HD + j];
    ebf[l * HD + j] = sb;
  }
}

// ---------------- node encoder: x = nf @ node_w + node_b  (K=64) ----------------
__global__ __launch_bounds__(256) void k_encode(
    const float* __restrict__ nf, const float* __restrict__ w,
    const float* __restrict__ b, float* __restrict__ x, int n) {
  __shared__ float As[32][64];
  __shared__ float Bs[32][128];
  const int t = threadIdx.x;
  const int eg = t & 15, og = t >> 4;
  const int e0 = eg * 4, j0 = og * 8;
  const int n0 = blockIdx.x * 64;

  float acc[4][8];
#pragma unroll
  for (int i = 0; i < 4; ++i)
#pragma unroll
    for (int j = 0; j < 8; ++j) acc[i][j] = 0.f;

  for (int c = 0; c < 2; ++c) {
    if (c) __syncthreads();
#pragma unroll
    for (int r = 0; r < 2; ++r) {
      int lin = r * 256 + t;
      int e = lin & 63, ks = (lin >> 6) * 4;
      int node = n0 + e; if (node >= n) node = n - 1;
      float4 v = *(const float4*)&nf[(size_t)node * 64 + c * 32 + ks];
      As[ks + 0][e] = v.x; As[ks + 1][e] = v.y; As[ks + 2][e] = v.z; As[ks + 3][e] = v.w;
    }
#pragma unroll
    for (int r = 0; r < 4; ++r) {
      int lin = r * 256 + t;
      int k = lin >> 5, jq = lin & 31;
      *(float4*)&Bs[k][jq * 4] = *(const float4*)&w[(size_t)(c * 32 + k) * HD + jq * 4];
    }
    __syncthreads();
#pragma unroll
    for (int k = 0; k < 32; ++k) {
      float4 a  = *(const float4*)&As[k][e0];
      float4 b0 = *(const float4*)&Bs[k][j0];
      float4 b1 = *(const float4*)&Bs[k][j0 + 4];
      fma_4x8(acc, a, b0, b1);
    }
  }
  float bias[8];
#pragma unroll
  for (int j = 0; j < 8; ++j) bias[j] = b[j0 + j];
#pragma unroll
  for (int ee = 0; ee < 4; ++ee) {
    int node = n0 + e0 + ee;
    if (node < n) {
      float4 o0 = make_float4(acc[ee][0] + bias[0], acc[ee][1] + bias[1],
                              acc[ee][2] + bias[2], acc[ee][3] + bias[3]);
      float4 o1 = make_float4(acc[ee][4] + bias[4], acc[ee][5] + bias[5],
                              acc[ee][6] + bias[6], acc[ee][7] + bias[7]);
      *(float4*)&x[(size_t)node * HD + j0]     = o0;
      *(float4*)&x[(size_t)node * HD + j0 + 4] = o1;
    }
  }
}

// ---------------- dual node GEMM: out1 = X@B1,  out2 = X@B2 + bias2 ----------------
__global__ __launch_bounds__(256) void k_ngemm2(
    const float* __restrict__ X, const float* __restrict__ B1,
    const float* __restrict__ B2, const float* __restrict__ bias2,
    float* __restrict__ out1, float* __restrict__ out2, int n) {
  __shared__ float As[32][64];
  __shared__ float Bs1[32][128];
  __shared__ float Bs2[32][128];
  const int t = threadIdx.x;
  const int eg = t & 15, og = t >> 4;
  const int e0 = eg * 4, j0 = og * 8;
  const int n0 = blockIdx.x * 64;

  float acc1[4][8], acc2[4][8];
#pragma unroll
  for (int i = 0; i < 4; ++i)
#pragma unroll
    for (int j = 0; j < 8; ++j) { acc1[i][j] = 0.f; acc2[i][j] = 0.f; }

  for (int c = 0; c < 4; ++c) {
    if (c) __syncthreads();
#pragma unroll
    for (int r = 0; r < 2; ++r) {
      int lin = r * 256 + t;
      int e = lin & 63, ks = (lin >> 6) * 4;
      int node = n0 + e; if (node >= n) node = n - 1;
      float4 v = *(const float4*)&X[(size_t)node * HD + c * 32 + ks];
      As[ks + 0][e] = v.x; As[ks + 1][e] = v.y; As[ks + 2][e] = v.z; As[ks + 3][e] = v.w;
    }
#pragma unroll
    for (int r = 0; r < 4; ++r) {
      int lin = r * 256 + t;
      int k = lin >> 5, jq = lin & 31;
      *(float4*)&Bs1[k][jq * 4] = *(const float4*)&B1[(size_t)(c * 32 + k) * HD + jq * 4];
      *(float4*)&Bs2[k][jq * 4] = *(const float4*)&B2[(size_t)(c * 32 + k) * HD + jq * 4];
    }
    __syncthreads();
#pragma unroll
    for (int k = 0; k < 32; ++k) {
      float4 a = *(const float4*)&As[k][e0];
      fma_4x8(acc1, a, *(const float4*)&Bs1[k][j0], *(const float4*)&Bs1[k][j0 + 4]);
      fma_4x8(acc2, a, *(const float4*)&Bs2[k][j0], *(const float4*)&Bs2[k][j0 + 4]);
    }
  }
  float bb[8];
#pragma unroll
  for (int j = 0; j < 8; ++j) bb[j] = bias2[j0 + j];
#pragma unroll
  for (int ee = 0; ee < 4; ++ee) {
    int node = n0 + e0 + ee;
    if (node < n) {
      *(float4*)&out1[(size_t)node * HD + j0] =
          make_float4(acc1[ee][0], acc1[ee][1], acc1[ee][2], acc1[ee][3]);
      *(float4*)&out1[(size_t)node * HD + j0 + 4] =
          make_float4(acc1[ee][4], acc1[ee][5], acc1[ee][6], acc1[ee][7]);
      *(float4*)&out2[(size_t)node * HD + j0] =
          make_float4(acc2[ee][0] + bb[0], acc2[ee][1] + bb[1],
                      acc2[ee][2] + bb[2], acc2[ee][3] + bb[3]);
      *(float4*)&out2[(size_t)node * HD + j0 + 4] =
          make_float4(acc2[ee][4] + bb[4], acc2[ee][5] + bb[5],
                      acc2[ee][6] + bb[6], acc2[ee][7] + bb[7]);
    }
  }
}

// ---------------- pull-CSR edge kernel (no atomics, software-pipelined) ----------------
// Hs[c] = rdeg[c] * sum_{e in in(c)} relu( xa[rowS[e]] + xbb[c] + efS[e] @ EW )
// One wave per node; lane owns 2 cols; EW in 64 VGPRs; next-edge xa/efS prefetched.
__global__ __launch_bounds__(256) void k_edge_pull(
    const float* __restrict__ xa, const float* __restrict__ xbb,
    const float* __restrict__ efS,
    const int* __restrict__ rowS,
    const int* __restrict__ rowptr,
    const float* __restrict__ EW,    // [32][128]
    const float* __restrict__ rdeg,
    float* __restrict__ Hs, int n) {
  const int lane = threadIdx.x & 63;
  const int node = blockIdx.x * 4 + (threadIdx.x >> 6);
  float2 ew[32];
#pragma unroll
  for (int k = 0; k < 32; ++k)
    ew[k] = *(const float2*)&EW[k * HD + lane * 2];
  if (node >= n) return;
  const int s = rowptr[node], en = rowptr[node + 1];
  const float2 xb2 = *(const float2*)&xbb[(size_t)node * HD + lane * 2];
  float accx = 0.f, accy = 0.f;

  if (s < en) {
    float4 q[8];
    float2 xc;
    {
      const float4* ep = (const float4*)efS + (size_t)s * 8;
#pragma unroll
      for (int i = 0; i < 8; ++i) q[i] = ep[i];
      xc = *(const float2*)&xa[(size_t)rowS[s] * HD + lane * 2];
    }
    for (int e = s; e < en - 1; ++e) {
      // prefetch e+1 (independent of the compute below; overlaps gather latency)
      float4 qn[8];
      const float4* ep = (const float4*)efS + (size_t)(e + 1) * 8;
#pragma unroll
      for (int i = 0; i < 8; ++i) qn[i] = ep[i];
      float2 xn = *(const float2*)&xa[(size_t)rowS[e + 1] * HD + lane * 2];
      // compute current
      float etx = 0.f, ety = 0.f;
#pragma unroll
      for (int i = 0; i < 8; ++i) {
        etx += q[i].x * ew[4 * i + 0].x + q[i].y * ew[4 * i + 1].x +
               q[i].z * ew[4 * i + 2].x + q[i].w * ew[4 * i + 3].x;
        ety += q[i].x * ew[4 * i + 0].y + q[i].y * ew[4 * i + 1].y +
               q[i].z * ew[4 * i + 2].y + q[i].w * ew[4 * i + 3].y;
      }
      accx += fmaxf(xc.x + xb2.x + etx, 0.f);
      accy += fmaxf(xc.y + xb2.y + ety, 0.f);
#pragma unroll
      for (int i = 0; i < 8; ++i) q[i] = qn[i];
      xc = xn;
    }
    // epilogue: last edge
    {
      float etx = 0.f, ety = 0.f;
#pragma unroll
      for (int i = 0; i < 8; ++i) {
        etx += q[i].x * ew[4 * i + 0].x + q[i].y * ew[4 * i + 1].x +
               q[i].z * ew[4 * i + 2].x + q[i].w * ew[4 * i + 3].x;
        ety += q[i].x * ew[4 * i + 0].y + q[i].y * ew[4 * i + 1].y +
               q[i].z * ew[4 * i + 2].y + q[i].w * ew[4 * i + 3].y;
      }
      accx += fmaxf(xc.x + xb2.x + etx, 0.f);
      accy += fmaxf(xc.y + xb2.y + ety, 0.f);
    }
  }
  const float rd = rdeg[node];
  float2 o; o.x = accx * rd; o.y = accy * rd;
  *(float2*)&Hs[(size_t)node * HD + lane * 2] = o;
}

// ---------------- fused: agg = Hs@W2 + b2*flag ; x_new = relu(relu([X|agg]@U1+b1)@U2+b2) ----
__global__ __launch_bounds__(256) void k_upd_fused(
    const float* __restrict__ X, const float* __restrict__ Hs,
    const float* __restrict__ w2m, const float* __restrict__ b2m,
    const float* __restrict__ flag,
    const float* __restrict__ u1, const float* __restrict__ ub1,
    const float* __restrict__ u2, const float* __restrict__ ub2,
    float* __restrict__ xout, int n) {
  __shared__ float As[32][64];
  __shared__ float Bs[32][128];
  __shared__ float Hl[128][64];   // agg^T, then hidden^T
  const int t = threadIdx.x;
  const int eg = t & 15, og = t >> 4;
  const int e0 = eg * 4, j0 = og * 8;
  const int n0 = blockIdx.x * 64;

  float acc[4][8];
#pragma unroll
  for (int i = 0; i < 4; ++i)
#pragma unroll
    for (int j = 0; j < 8; ++j) acc[i][j] = 0.f;

  // Phase A: agg^T = (Hs@w2m + b2m*flag)^T  -> Hl
  for (int c = 0; c < 4; ++c) {
    if (c) __syncthreads();
#pragma unroll
    for (int r = 0; r < 2; ++r) {
      int lin = r * 256 + t;
      int e = lin & 63, ks = (lin >> 6) * 4;
      int node = n0 + e; if (node >= n) node = n - 1;
      float4 v = *(const float4*)&Hs[(size_t)node * HD + c * 32 + ks];
      As[ks + 0][e] = v.x; As[ks + 1][e] = v.y; As[ks + 2][e] = v.z; As[ks + 3][e] = v.w;
    }
#pragma unroll
    for (int r = 0; r < 4; ++r) {
      int lin = r * 256 + t;
      int k = lin >> 5, jq = lin & 31;
      *(float4*)&Bs[k][jq * 4] = *(const float4*)&w2m[(size_t)(c * 32 + k) * HD + jq * 4];
    }
    __syncthreads();
#pragma unroll
    for (int k = 0; k < 32; ++k) {
      float4 a = *(const float4*)&As[k][e0];
      fma_4x8(acc, a, *(const float4*)&Bs[k][j0], *(const float4*)&Bs[k][j0 + 4]);
    }
  }
  {
    float fl[4];
#pragma unroll
    for (int ee = 0; ee < 4; ++ee) {
      int node = n0 + e0 + ee; if (node >= n) node = n - 1;
      fl[ee] = flag[node];
    }
#pragma unroll
    for (int jj = 0; jj < 8; ++jj) {
      float bb = b2m[j0 + jj];
      float4 h = make_float4(acc[0][jj] + bb * fl[0], acc[1][jj] + bb * fl[1],
                             acc[2][jj] + bb * fl[2], acc[3][jj] + bb * fl[3]);
      *(float4*)&Hl[j0 + jj][e0] = h;
    }
  }
  __syncthreads();  // Hl ready; also As/Bs free to restage

  // Phase B: K=256 over [X | Hl]
#pragma unroll
  for (int i = 0; i < 4; ++i)
#pragma unroll
    for (int j = 0; j < 8; ++j) acc[i][j] = 0.f;
  for (int c = 0; c < 8; ++c) {
    if (c) __syncthreads();
    if (c < 4) {
#pragma unroll
      for (int r = 0; r < 2; ++r) {
        int lin = r * 256 + t;
        int e = lin & 63, ks = (lin >> 6) * 4;
        int node = n0 + e; if (node >= n) node = n - 1;
        float4 v = *(const float4*)&X[(size_t)node * HD + c * 32 + ks];
        As[ks + 0][e] = v.x; As[ks + 1][e] = v.y; As[ks + 2][e] = v.z; As[ks + 3][e] = v.w;
      }
    }
#pragma unroll
    for (int r = 0; r < 4; ++r) {
      int lin = r * 256 + t;
      int k = lin >> 5, jq = lin & 31;
      *(float4*)&Bs[k][jq * 4] = *(const float4*)&u1[(size_t)(c * 32 + k) * HD + jq * 4];
    }
    __syncthreads();
    if (c < 4) {
#pragma unroll
      for (int k = 0; k < 32; ++k) {
        float4 a = *(const float4*)&As[k][e0];
        fma_4x8(acc, a, *(const float4*)&Bs[k][j0], *(const float4*)&Bs[k][j0 + 4]);
      }
    } else {
#pragma unroll
      for (int k = 0; k < 32; ++k) {
        float4 a = *(const float4*)&Hl[(c - 4) * 32 + k][e0];
        fma_4x8(acc, a, *(const float4*)&Bs[k][j0], *(const float4*)&Bs[k][j0 + 4]);
      }
    }
  }
  __syncthreads();  // all reads of Hl done
#pragma unroll
  for (int jj = 0; jj < 8; ++jj) {
    float bb = ub1[j0 + jj];
    float4 h = make_float4(fmaxf(acc[0][jj] + bb, 0.f), fmaxf(acc[1][jj] + bb, 0.f),
                           fmaxf(acc[2][jj] + bb, 0.f), fmaxf(acc[3][jj] + bb, 0.f));
    *(float4*)&Hl[j0 + jj][e0] = h;
  }
  __syncthreads();  // hidden ready; Bs free

  // Phase C: K=128 from Hl
#pragma unroll
  for (int i = 0; i < 4; ++i)
#pragma unroll
    for (int j = 0; j < 8; ++j) acc[i][j] = 0.f;
  for (int c = 0; c < 4; ++c) {
    if (c) __syncthreads();
#pragma unroll
    for (int r = 0; r < 4; ++r) {
      int lin = r * 256 + t;
      int k = lin >> 5, jq = lin & 31;
      *(float4*)&Bs[k][jq * 4] = *(const float4*)&u2[(size_t)(c * 32 + k) * HD + jq * 4];
    }
    __syncthreads();
#pragma unroll
    for (int k = 0; k < 32; ++k) {
      float4 a = *(const float4*)&Hl[c * 32 + k][e0];
      fma_4x8(acc, a, *(const float4*)&Bs[k][j0], *(const float4*)&Bs[k][j0 + 4]);
    }
  }
  float bias2[8];
#pragma unroll
  for (int jj = 0; jj < 8; ++jj) bias2[jj] = ub2[j0 + jj];
#pragma unroll
  for (int ee = 0; ee < 4; ++ee) {
    int node = n0 + e0 + ee;
    if (node < n) {
      float4 o0 = make_float4(fmaxf(acc[ee][0] + bias2[0], 0.f), fmaxf(acc[ee][1] + bias2[1], 0.f),
                              fmaxf(acc[ee][2] + bias2[2], 0.f), fmaxf(acc[ee][3] + bias2[3], 0.f));
      float4 o1 = make_float4(fmaxf(acc[ee][4] + bias2[4], 0.f), fmaxf(acc[ee][5] + bias2[5], 0.f),
                              fmaxf(acc[ee][6] + bias2[6], 0.f), fmaxf(acc[ee][7] + bias2[7], 0.f));
      *(float4*)&xout[(size_t)node * HD + j0]     = o0;
      *(float4*)&xout[(size_t)node * HD + j0 + 4] = o1;
    }
  }
}

// ---------------- readout: out = relu(pooled @ ro_w1 + b1) @ ro_w2 + b2 ----------------
__global__ void k_readout(const float* __restrict__ pooled,
                          const float* __restrict__ w1, const float* __restrict__ b1,
                          const float* __restrict__ w2, const float* __restrict__ b2,
                          float* __restrict__ out) {
  __shared__ float P[16][128];
  __shared__ float Hh[16][128];
  int t = threadIdx.x;
  int g = t >> 4;
  int jo = (t & 15) * 8;
#pragma unroll
  for (int i = 0; i < 8; ++i) {
    int idx = t * 8 + i;
    int gg = idx >> 7, j = idx & 127;
    P[gg][j] = pooled[idx];
  }
  __syncthreads();
  float h[8];
#pragma unroll
  for (int jj = 0; jj < 8; ++jj) h[jj] = b1[jo + jj];
  for (int k = 0; k < 128; ++k) {
    float p = P[g][k];
#pragma unroll
    for (int jj = 0; jj < 8; ++jj) h[jj] += p * w1[(size_t)k * HD + jo + jj];
  }
#pragma unroll
  for (int jj = 0; jj < 8; ++jj) Hh[g][jo + jj] = fmaxf(h[jj], 0.f);
  __syncthreads();
  float o[8];
#pragma unroll
  for (int jj = 0; jj < 8; ++jj) o[jj] = b2[jo + jj];
  for (int k = 0; k < 128; ++k) {
    float hv = Hh[g][k];
#pragma unroll
    for (int jj = 0; jj < 8; ++jj) o[jj] += hv * w2[(size_t)k * HD + jo + jj];
  }
#pragma unroll
  for (int jj = 0; jj < 8; ++jj) out[g * HD + jo + jj] = o[jj];
}

// ---------------- launcher ----------------
extern "C" void kernel_launch(void* const* d_in, const int* in_sizes, int n_in,
                              void* d_out, int out_size, void* d_ws, size_t ws_size,
                              hipStream_t stream) {
  const float* nf     = (const float*)d_in[0];
  const int*   ei     = (const int*)d_in[1];
  const float* ef     = (const float*)d_in[2];
  const int*   batch  = (const int*)d_in[3];
  const float* node_w = (const float*)d_in[4];
  const float* node_b = (const float*)d_in[5];
  const float* edge_w = (const float*)d_in[6];
  const float* edge_b = (const float*)d_in[7];
  const float* msg_w1 = (const float*)d_in[8];
  const float* msg_b1 = (const float*)d_in[9];
  const float* msg_w2 = (const float*)d_in[10];
  const float* msg_b2 = (const float*)d_in[11];
  const float* upd_w1 = (const float*)d_in[12];
  const float* upd_b1 = (const float*)d_in[13];
  const float* upd_w2 = (const float*)d_in[14];
  const float* upd_b2 = (const float*)d_in[15];
  const float* ro_w1  = (const float*)d_in[16];
  const float* ro_b1  = (const float*)d_in[17];
  const float* ro_w2  = (const float*)d_in[18];
  const float* ro_b2  = (const float*)d_in[19];

  const int N = in_sizes[3];
  const int E = in_sizes[1] / 2;
  const int* rowp = ei;
  const int* colp = ei + E;
  const size_t NH = (size_t)N * HD;

  float* w = (float*)d_ws;
  float* P0 = w; w += NH;   // X (even layers)
  float* P1 = w; w += NH;   // xa
  float* P2 = w; w += NH;   // xbb
  float* P3 = w; w += NH;   // Hs
  float* P4 = w; w += NH;   // X (odd layers)
  float* efS  = w; w += (size_t)E * 32;  // permuted edge features
  float* rdeg = w; w += N;
  float* flag = w; w += N;
  float* ewf  = w; w += 3 * 32 * HD;
  float* ebf  = w; w += 3 * HD;
  float* pooled = w; w += 16 * HD;
  int* cnt    = (int*)w; w += N;
  int* cursor = (int*)w; w += N;
  int* rowptr = (int*)w; w += (N + 1);
  int* gstart = (int*)w; w += 17;
  int* rowS   = (int*)w; w += E;
  int* permS  = (int*)w; w += E;
  (void)ws_size; (void)n_in; (void)out_size;

  hipMemsetAsync(cnt, 0, N * sizeof(int), stream);

  k_fold_edge<<<3, 256, 0, stream>>>(edge_w, edge_b, msg_w1, msg_b1, ewf, ebf);
  k_encode<<<(N + 63) / 64, 256, 0, stream>>>(nf, node_w, node_b, P0, N);
  k_cnt<<<(E + 255) / 256, 256, 0, stream>>>(colp, cnt, E);
  k_rdeg_flag<<<(N + 255) / 256, 256, 0, stream>>>(cnt, rdeg, flag, N);
  k_scan<<<1, 1024, 0, stream>>>(cnt, N, cursor, rowptr);
  k_scatter<<<(E + 255) / 256, 256, 0, stream>>>(rowp, colp, cursor, rowS, permS, E);
  k_permute_ef<<<(E * 8 + 255) / 256, 256, 0, stream>>>(ef, permS, efS, E);
  k_bounds<<<1, 64, 0, stream>>>(batch, gstart, N);

  const int ngrid = (N + 63) / 64;
  float* X = P0;
  float* Xn = P4;
  for (int l = 0; l < 3; ++l) {
    const float* W1a = msg_w1 + (size_t)l * 384 * HD;
    const float* W1b = W1a + (size_t)HD * HD;
    k_ngemm2<<<ngrid, 256, 0, stream>>>(X, W1a, W1b, ebf + l * HD, P1, P2, N);
    k_edge_pull<<<(N + 3) / 4, 256, 0, stream>>>(P1, P2, efS, rowS, rowptr,
                                                 ewf + (size_t)l * 32 * HD, rdeg, P3, N);
    k_upd_fused<<<ngrid, 256, 0, stream>>>(X, P3,
        msg_w2 + (size_t)l * HD * HD, msg_b2 + l * HD, flag,
        upd_w1 + (size_t)l * 256 * HD, upd_b1 + l * HD,
        upd_w2 + (size_t)l * HD * HD, upd_b2 + l * HD, Xn, N);
    float* tmp = X; X = Xn; Xn = tmp;
  }

  k_pool_seg<<<64, 256, 0, stream>>>(X, gstart, pooled);
  k_readout<<<1, 256, 0, stream>>>(pooled, ro_w1, ro_b1, ro_w2, ro_b2, (float*)d_out);
}